// Round 12
// baseline (304.729 us; speedup 1.0000x reference)
//
#include <hip/hip_runtime.h>
#include <math.h>

#define BRR 512
#define LLL 64
#define KKK 16
#define EEE 64
#define CC2 8
#define PPP 1024
#define BN_EPS 1e-5f
#define NSTRIPE 16

__device__ __forceinline__ float relu_f(float v){ return v>0.f?v:0.f; }
// Row-padded W1 layout: stride 68 + 4-float stagger per 8-row octet.
__device__ __forceinline__ int lds_row(int r){ return r*68 + (((r>>3)&7)<<2); }

// ---- d_ws float layout ----
#define OFF_HBL  0u          // [(b*64+l)*8+c2]            262144
#define OFF_HBK  262144u     // [(b*16+k)*8+c2]             65536
#define OFF_Y0   327680u     // [b*1024 + k*64+c]          524288
#define OFF_X1   851968u     // [(b*64+l)*64+c] M0L->X1   2097152
#define OFF_Y1   2949120u    // [b*1024 + k*64+o] M0K->Y1  524288
#define OFF_X2   3473408u    // [(b*64+l)*8+o2]            262144
#define OFF_Y2   3735552u    // [(b*16+k)*8+o2]             65536
#define OFF_M1L  3801088u    // pre-pass1: x0 (X08); post: raw k-mean of T1
#define OFF_M1K  5898240u    // [b*1024 + k*64+c] raw l-mean half0   524288
#define OFF_SUM0 6422528u
#define OFF_SSQ0 6423552u
#define OFF_SUM1 6424576u
#define OFF_SSQ1 6425600u
#define OFF_S0   6426624u
#define OFF_T0   6426688u
#define OFF_S1   6426752u
#define OFF_T1   6426816u
#define WS_FLOATS 6426880u   // 25,707,520 bytes (small/fallback footprint)
// ---- big-ws extension (only touched when ws_size >= WS_BIG*4) ----
#define OFF_M1KB 6426880u    // M1K half1 partial                    524288
#define OFF_T1S  6951168u    // raw T1 tiles, c-major: [(b*8+pblk)*8192 + c*128 + p]
#define WS_BIG   40505600u   // 162,022,400 bytes (~154.5 MiB)

// Inline BN0/BN1 finalize (redundant per block; same math as k_bn).
__device__ __forceinline__ void bn_inline(const float* __restrict__ ws,
                                          unsigned sumOff,
                                          const float* __restrict__ g_,
                                          const float* __restrict__ b_,
                                          int tid, float* sc_out, float* st_out){
  if (tid < 64){
    float s=0.f, ss=0.f;
    for (int i=0;i<NSTRIPE;++i){ s+=ws[sumOff+i*64+tid]; ss+=ws[sumOff+1024+i*64+tid]; }
    const float invN = 1.0f/((float)BRR*LLL*KKK);
    float mu=s*invN, var=ss*invN-mu*mu;
    float sc = g_[tid]/sqrtf(var+BN_EPS);
    sc_out[tid]=sc;
    st_out[tid]=b_[tid]-mu*sc;
  }
}

// ---------------------------------------------------------------------------
// K0: zero stat accumulators only (4096 floats).
__global__ void k_zero(float4* __restrict__ p, int n4){
  int t = blockIdx.x*256 + threadIdx.x;
  if (t < n4) p[t] = make_float4(0.f,0.f,0.f,0.f);
}

// K1: per-b prep. HbL,HbK,y0,M0K,M0L + BN0 channel sums. Also stores x0
// (=X08) into the pre-pass1-dead OFF_M1L region. float4 staging/stores (G13).
__global__ __launch_bounds__(256) void k_prep(const float* __restrict__ Hr,
                                              const float* __restrict__ Hi,
                                              const float* __restrict__ P40,
                                              float* __restrict__ ws){
  __shared__ float sm[9344];
  int b = blockIdx.x, tid = threadIdx.x;
  const float* hrg = Hr + (size_t)b*4096;
  const float* hig = Hi + (size_t)b*4096;
  for (int t4=tid;t4<1024;t4+=256){
    *(float4*)&sm[t4*4]      = *(const float4*)&hrg[t4*4];
    *(float4*)&sm[4096+t4*4] = *(const float4*)&hig[t4*4];
  }
  for (int t=tid;t<512;t+=256){ int c=t&63,j=t>>6; sm[8192+j*64+c]=P40[c*8+j]; }
  __syncthreads();
  for (int t=tid;t<512;t+=256){ int l=t>>3,c2=t&7;          // HbL [8704,9216)
    const float* src=sm+((c2<4)?0:4096); int u=c2&3;
    float s=0.f;
    #pragma unroll
    for(int k=0;k<16;++k) s+=src[(l*16+k)*4+u];
    sm[8704+t]=s*(1.f/16.f); }
  for (int t=tid;t<128;t+=256){ int k=t>>3,c2=t&7;          // HbK [9216,9344)
    const float* src=sm+((c2<4)?0:4096); int u=c2&3;
    float s=0.f;
    for(int l=0;l<64;++l) s+=src[(l*16+k)*4+u];
    sm[9216+t]=s*(1.f/64.f); }
  __syncthreads();
  for (int t=tid;t<1024;t+=256){ int k=t>>6,c=t&63; float s=0.f;   // y0 [4096,5120)
    #pragma unroll
    for(int j=0;j<8;++j) s+=sm[8192+j*64+c]*sm[9216+k*8+j];
    sm[4096+t]=0.1f*s; }
  for (int t=tid;t<4096;t+=256){ int l=t>>6,c=t&63; float s=0.f;   // x0 [0,4096)
    #pragma unroll
    for(int j=0;j<8;++j) s+=sm[8192+j*64+c]*sm[8704+l*8+j];
    sm[t]=0.1f*s; }
  __syncthreads();
  for (int t=tid;t<1024;t+=256){ int c=t&63; float yv=sm[4096+t]; float s=0.f;  // M0K [5120,6144)
    for(int l=0;l<64;++l) s+=relu_f(sm[l*64+c]+yv);
    sm[5120+t]=s*(1.f/64.f); }
  float ssum=0.f, ssq=0.f;                       // channel c = tid&63 (stride 256 preserves it)
  for (int t=tid;t<4096;t+=256){ int c=t&63; float xv=sm[t]; float s=0.f;
    #pragma unroll
    for(int k=0;k<16;++k){ float v=relu_f(xv+sm[4096+k*64+c]); s+=v; ssq+=v*v; }
    ssum+=s;
    ws[OFF_X1+(size_t)b*4096+t]=s*(1.f/16.f); }  // M0L
  __syncthreads();
  sm[6144+tid]=ssum; sm[6400+tid]=ssq;
  __syncthreads();
  if (tid<64){
    float ts =sm[6144+tid]+sm[6208+tid]+sm[6272+tid]+sm[6336+tid];
    float tss=sm[6400+tid]+sm[6464+tid]+sm[6528+tid]+sm[6592+tid];
    int stripe = b & (NSTRIPE-1);
    atomicAdd(&ws[OFF_SUM0+stripe*64+tid], ts);
    atomicAdd(&ws[OFF_SSQ0+stripe*64+tid], tss);
  }
  for (int t4=tid;t4<128;t4+=256)
    *(float4*)&ws[OFF_HBL+(size_t)b*512+t4*4] = *(const float4*)&sm[8704+t4*4];
  for (int t=tid;t<128;t+=256)  ws[OFF_HBK+(size_t)b*128+t]=sm[9216+t];
  for (int t4=tid;t4<256;t4+=256)
    *(float4*)&ws[OFF_Y0+(size_t)b*1024+t4*4] = *(const float4*)&sm[4096+t4*4];
  for (int t4=tid;t4<256;t4+=256)
    *(float4*)&ws[OFF_Y1+(size_t)b*1024+t4*4] = *(const float4*)&sm[5120+t4*4];   // M0K
  for (int t4=tid;t4<1024;t4+=256)
    *(float4*)&ws[OFF_M1L+(size_t)b*4096+t4*4] = *(const float4*)&sm[t4*4];       // x0
}

// K2: finalize BN -> s,t (small path only; big path inlines).
__global__ void k_bn(float* __restrict__ ws, const float* __restrict__ g_,
                     const float* __restrict__ b_, unsigned sumOff, unsigned outOff){
  int tid = threadIdx.x;
  bn_inline(ws, sumOff, g_, b_, tid, ws+outOff, ws+outOff+64);
}

// K3: X1/Y1 in place over M0L/M0K. BN0 inlined; coalesced float4 P21 staging
// into stride-65 transposed wt (writer 2-way = free, reader conflict-free).
__global__ __launch_bounds__(256) void k_xy1(float* __restrict__ ws,
                                             const float* __restrict__ P21,
                                             const float* __restrict__ P41,
                                             const float* __restrict__ g0,
                                             const float* __restrict__ b0){
  __shared__ float wt[4160], p41[512], mrow[1024], hbs[128], s0l[64], t0l[64];
  int bx = blockIdx.x, tid = threadIdx.x;
  for (int t4=tid;t4<1024;t4+=256){           // wt[c*65+o] = 2*P21[o*64+c]
    int o=t4>>4, c4=(t4&15)*4;
    float4 v = *(const float4*)&P21[o*64+c4];
    wt[(c4+0)*65+o]=2.f*v.x; wt[(c4+1)*65+o]=2.f*v.y;
    wt[(c4+2)*65+o]=2.f*v.z; wt[(c4+3)*65+o]=2.f*v.w;
  }
  for (int t=tid;t<512;t+=256)  p41[t] = P41[t];                        // [o*8+j]
  bn_inline(ws, OFF_SUM0, g0, b0, tid, s0l, t0l);
  bool isX = bx < 2048;
  int row0 = isX ? bx*16 : (bx-2048)*16;
  if (isX){
    for (int t4=tid;t4<256;t4+=256)
      *(float4*)&mrow[t4*4] = *(const float4*)&ws[OFF_X1+(size_t)row0*64+t4*4];
    if (tid<128) hbs[tid] = ws[OFF_HBL+(size_t)row0*8+tid];
  } else {
    for (int t4=tid;t4<256;t4+=256)
      *(float4*)&mrow[t4*4] = *(const float4*)&ws[OFF_Y1+(size_t)row0*64+t4*4];
    if (tid<128) hbs[tid] = ws[OFF_HBK+(size_t)row0*8+tid];
  }
  __syncthreads();
  for (int t=tid;t<1024;t+=256){ int c=t&63; mrow[t]=s0l[c]*mrow[t]+t0l[c]; }
  __syncthreads();
  int r4 = tid>>6, o = tid&63;
  #pragma unroll
  for (int rr=0;rr<4;++rr){
    int rl = rr*4 + r4;
    float s=0.f;
    for (int c=0;c<64;++c) s += wt[c*65+o]*mrow[rl*64+c];
    float s2=0.f;
    #pragma unroll
    for (int j=0;j<8;++j) s2 += p41[o*8+j]*hbs[rl*8+j];
    float res = s + 0.1f*s2;
    if (isX) ws[OFF_X1+(size_t)(row0+rl)*64+o] = res;
    else     ws[OFF_Y1+(size_t)(row0+rl)*64+o] = res;
  }
}

// ---- T1 tile LDS map (small-path t1_tile) ----
#define T_W1   0
#define T_X08  4384
#define T_Y0   4896
#define T_X1   5984
#define T_Y1   6496
#define T_S0   7520
#define T_T0   7584
#define T_P4T0 7648
#define T_HB8  8160
#define T_END  8224

// c4 loop unroll-4: full x16 unroll -> VGPR 256 tier (r3); unroll 4 -> 76 (r4).
__device__ void t1_tile(float* sm, const float* __restrict__ ws,
                        const float* __restrict__ P11, const float* __restrict__ P40,
                        int b, int pblk, int tid,
                        float acc[8][4], int og, int pg, int lloc, int c0){
  for (int t=tid;t<4096;t+=256){ int o=t>>6,c=t&63; sm[T_W1+lds_row(o)+c]=2.0f*P11[t]; }
  for (int t=tid;t<1024;t+=256){ int k=t>>6,c=t&63; sm[T_Y0+k*68+c]=ws[OFF_Y0+(size_t)b*1024+t]; }
  for (int t=tid;t<512;t+=256)  sm[T_X1+t]=ws[OFF_X1+((size_t)b*64+pblk*8)*64+t];
  for (int t=tid;t<1024;t+=256) sm[T_Y1+t]=ws[OFF_Y1+(size_t)b*1024+t];
  for (int t=tid;t<512;t+=256){ int c=t&63,j=t>>6; sm[T_P4T0+j*64+c]=P40[c*8+j]; }
  if (tid<64){ sm[T_S0+tid]=ws[OFF_S0+tid]; sm[T_T0+tid]=ws[OFF_T0+tid]; }
  else if (tid<128){ int t2=tid-64; sm[T_HB8+t2]=ws[OFF_HBL+((size_t)b*64+pblk*8)*8+t2]; }
  __syncthreads();
  for (int e=tid;e<512;e+=256){ int l=e>>6,c=e&63; float s=0.f;
    #pragma unroll
    for(int j=0;j<8;++j) s += sm[T_P4T0+j*64+c]*sm[T_HB8+l*8+j];
    sm[T_X08+e]=0.1f*s; }
  __syncthreads();
  {
    float xb[8];
    *(float4*)&xb[0] = *(const float4*)&sm[T_X1 + lloc*64 + c0];
    *(float4*)&xb[4] = *(const float4*)&sm[T_X1 + lloc*64 + c0 + 4];
    #pragma unroll
    for (int i=0;i<4;++i){
      int k=(pg&3)*4+i;
      float yb[8];
      *(float4*)&yb[0] = *(const float4*)&sm[T_Y1 + k*64 + c0];
      *(float4*)&yb[4] = *(const float4*)&sm[T_Y1 + k*64 + c0 + 4];
      #pragma unroll
      for (int j=0;j<8;++j) acc[j][i]=xb[j]+yb[j];
    }
  }
  #pragma unroll 4
  for (int c4=0;c4<16;++c4){
    float4 xr  = *(const float4*)&sm[T_X08 + lloc*64 + c4*4];
    float4 s0v = *(const float4*)&sm[T_S0 + c4*4];
    float4 t0v = *(const float4*)&sm[T_T0 + c4*4];
    float4 aa[4];
    #pragma unroll
    for (int i=0;i<4;++i){
      int k=(pg&3)*4+i;
      float4 yr = *(const float4*)&sm[T_Y0 + k*68 + c4*4];
      aa[i].x = s0v.x*relu_f(xr.x+yr.x)+t0v.x;
      aa[i].y = s0v.y*relu_f(xr.y+yr.y)+t0v.y;
      aa[i].z = s0v.z*relu_f(xr.z+yr.z)+t0v.z;
      aa[i].w = s0v.w*relu_f(xr.w+yr.w)+t0v.w;
    }
    #pragma unroll
    for (int j=0;j<8;++j){
      float4 w = *(const float4*)&sm[T_W1 + lds_row(c0+j) + c4*4];
      #pragma unroll
      for (int i=0;i<4;++i)
        acc[j][i] += w.x*aa[i].x + w.y*aa[i].y + w.z*aa[i].z + w.w*aa[i].w;
    }
  }
  #pragma unroll
  for (int j=0;j<8;++j)
    #pragma unroll
    for (int i=0;i<4;++i) acc[j][i] = relu_f(acc[j][i]);
}

// ---- pass1f LDS map (big path, pair-slot X1/X08) ----
#define PD_W1   0      // [0,4384)  padded W (lds_row)
#define PD_Y0   4384   // [4384,5472)  16 x 68
#define PD_Y1   5472   // [5472,6496)
#define PD_X1D  6496   // [6496,7520)  2 slots x 512 (pblk pair)
#define PD_X08D 7520   // [7520,8544)  2 slots x 512
#define PD_CT   8544   // [8544,8608)
#define PD_S0   8608   // [8608,8672)
#define PD_T0   8672   // [8672,8736)
#define PD_TOT  8736   // 34.9 KB -> 4 blocks/CU

// K4-BIG v7: r10's pair-blocked kernel; T1 spill now C-MAJOR per tile
// ([c][p], p=l*16+k) so k_final_big can stage with ds_write_b128 instead of
// 4x scalar scatter. Store = one float4 per (j,tile): addr (c0+j)*128 +
// lloc*16 + kg*4 (i contiguous). Wave coalescing: 8x128B segments.
__global__ __launch_bounds__(256) void k_pass1f(float* __restrict__ ws,
                                                const float* __restrict__ P11,
                                                const float* __restrict__ g0,
                                                const float* __restrict__ b0){
  __shared__ float sm[PD_TOT];
  int b = blockIdx.x >> 1, h = blockIdx.x & 1;
  int pb0 = h*4;
  int tid=threadIdx.x;
  int og=tid&7, kg=(tid>>3)&3, lloc=tid>>5, c0=og*8, wv=tid>>6;
  // stage W (2*P11, float4), Y0 (stride 68), Y1; BN0 finalize inline
  for (int t4=tid;t4<1024;t4+=256){ int o=t4>>4,c=(t4&15)*4;
    float4 v = *(const float4*)&P11[o*64+c];
    v.x*=2.f; v.y*=2.f; v.z*=2.f; v.w*=2.f;
    *(float4*)&sm[PD_W1+lds_row(o)+c]=v; }
  for (int t4=tid;t4<256;t4+=256){
    float4 v = *(const float4*)&ws[OFF_Y0+(size_t)b*1024+t4*4];
    *(float4*)&sm[PD_Y0+(t4>>4)*68+((t4&15)*4)]=v; }
  for (int t4=tid;t4<256;t4+=256)
    *(float4*)&sm[PD_Y1+t4*4] = *(const float4*)&ws[OFF_Y1+(size_t)b*1024+t4*4];
  bn_inline(ws, OFF_SUM0, g0, b0, tid, sm+PD_S0, sm+PD_T0);
  // prologue: slots <- pair0 (pb0, pb0+1).
  {
    int po = tid>>7, idx = tid&127;
    float4 v1 = *(const float4*)&ws[OFF_X1 +((size_t)b*64+(pb0+po)*8)*64 + (size_t)idx*4];
    float4 v8 = *(const float4*)&ws[OFF_M1L+((size_t)b*64+(pb0+po)*8)*64 + (size_t)idx*4];
    *(float4*)&sm[PD_X1D  + po*512 + idx*4] = v1;
    *(float4*)&sm[PD_X08D + po*512 + idx*4] = v8;
  }
  __syncthreads();
  if (tid<64){                       // ct[o] from UNSCALED W
    float ct=0.f;
    for (int c=0;c<64;++c) ct += sm[PD_W1+lds_row(tid)+c]*sm[PD_T0+c];
    sm[PD_CT+tid]=ct;
  }
  __syncthreads();
  for (int t4=tid;t4<1024;t4+=256){ int o=t4>>4,c=(t4&15)*4;
    float4 w = *(float4*)&sm[PD_W1+lds_row(o)+c];
    float4 s = *(const float4*)&sm[PD_S0+c];
    w.x*=s.x; w.y*=s.y; w.z*=s.z; w.w*=s.w;
    *(float4*)&sm[PD_W1+lds_row(o)+c]=w; }
  float qsum[8], mk[8][4];
  #pragma unroll
  for (int j=0;j<8;++j){ qsum[j]=0.f;
    #pragma unroll
    for (int i=0;i<4;++i) mk[j][i]=0.f; }
  #pragma unroll 1
  for (int pr=0;pr<2;++pr){
    int pblkA = pb0 + 2*pr, pblkB = pblkA + 1;
    __syncthreads();   // slots ready (prologue / prev mid-pair write); W-scale done
    float4 n1, n8;     // prefetch next pair into regs (T14 split)
    if (pr==0){
      int po = tid>>7, idx = tid&127, pn = pb0 + 2 + po;
      n1 = *(const float4*)&ws[OFF_X1 +((size_t)b*64+pn*8)*64 + (size_t)idx*4];
      n8 = *(const float4*)&ws[OFF_M1L+((size_t)b*64+pn*8)*64 + (size_t)idx*4];
    }
    float accA[8][4], accB[8][4];
    {
      float xbA[8], xbB[8], ctv[8];
      *(float4*)&xbA[0] = *(const float4*)&sm[PD_X1D       + lloc*64 + c0];
      *(float4*)&xbA[4] = *(const float4*)&sm[PD_X1D       + lloc*64 + c0 + 4];
      *(float4*)&xbB[0] = *(const float4*)&sm[PD_X1D + 512 + lloc*64 + c0];
      *(float4*)&xbB[4] = *(const float4*)&sm[PD_X1D + 512 + lloc*64 + c0 + 4];
      *(float4*)&ctv[0] = *(const float4*)&sm[PD_CT + c0];
      *(float4*)&ctv[4] = *(const float4*)&sm[PD_CT + c0 + 4];
      #pragma unroll
      for (int i=0;i<4;++i){
        int k=kg*4+i;
        float yb[8];
        *(float4*)&yb[0] = *(const float4*)&sm[PD_Y1 + k*64 + c0];
        *(float4*)&yb[4] = *(const float4*)&sm[PD_Y1 + k*64 + c0 + 4];
        #pragma unroll
        for (int j=0;j<8;++j){
          float base = yb[j]+ctv[j];
          accA[j][i]=xbA[j]+base;
          accB[j][i]=xbB[j]+base;
        }
      }
    }
    #pragma unroll 2
    for (int c4=0;c4<16;++c4){
      float4 xrA = *(const float4*)&sm[PD_X08D       + lloc*64 + c4*4];
      float4 xrB = *(const float4*)&sm[PD_X08D + 512 + lloc*64 + c4*4];
      float4 aaA[4], aaB[4];
      #pragma unroll
      for (int i=0;i<4;++i){
        int k=kg*4+i;
        float4 yr = *(const float4*)&sm[PD_Y0 + k*68 + c4*4];
        aaA[i].x = relu_f(xrA.x+yr.x); aaB[i].x = relu_f(xrB.x+yr.x);
        aaA[i].y = relu_f(xrA.y+yr.y); aaB[i].y = relu_f(xrB.y+yr.y);
        aaA[i].z = relu_f(xrA.z+yr.z); aaB[i].z = relu_f(xrB.z+yr.z);
        aaA[i].w = relu_f(xrA.w+yr.w); aaB[i].w = relu_f(xrB.w+yr.w);
      }
      #pragma unroll
      for (int j=0;j<8;++j){
        float4 w = *(const float4*)&sm[PD_W1 + lds_row(c0+j) + c4*4];
        #pragma unroll
        for (int i=0;i<4;++i){
          accA[j][i] += w.x*aaA[i].x + w.y*aaA[i].y + w.z*aaA[i].z + w.w*aaA[i].w;
          accB[j][i] += w.x*aaB[i].x + w.y*aaB[i].y + w.z*aaB[i].z + w.w*aaB[i].w;
        }
      }
    }
    #pragma unroll
    for (int j=0;j<8;++j)
      #pragma unroll
      for (int i=0;i<4;++i){
        accA[j][i] = relu_f(accA[j][i]);
        accB[j][i] = relu_f(accB[j][i]);
      }
    // ---- raw-T1 spill, c-major: float4 at (c0+j)*128 + lloc*16 + kg*4 ----
    {
      size_t tbA = OFF_T1S + ((size_t)b*8 + pblkA)*8192 + (size_t)(lloc*16 + kg*4);
      size_t tbB = OFF_T1S + ((size_t)b*8 + pblkB)*8192 + (size_t)(lloc*16 + kg*4);
      #pragma unroll
      for (int j=0;j<8;++j){
        *(float4*)&ws[tbA + (size_t)(c0+j)*128] =
          make_float4(accA[j][0],accA[j][1],accA[j][2],accA[j][3]);
        *(float4*)&ws[tbB + (size_t)(c0+j)*128] =
          make_float4(accB[j][0],accB[j][1],accB[j][2],accB[j][3]);
      }
    }
    // ---- fold into running register reductions (both tiles) ----
    float sjA[8], sjB[8];
    #pragma unroll
    for (int j=0;j<8;++j){
      sjA[j]=accA[j][0]+accA[j][1]+accA[j][2]+accA[j][3];
      sjB[j]=accB[j][0]+accB[j][1]+accB[j][2]+accB[j][3];
      qsum[j]+=accA[j][0]*accA[j][0]+accA[j][1]*accA[j][1]+accA[j][2]*accA[j][2]+accA[j][3]*accA[j][3];
      qsum[j]+=accB[j][0]*accB[j][0]+accB[j][1]*accB[j][1]+accB[j][2]*accB[j][2]+accB[j][3]*accB[j][3];
      #pragma unroll
      for (int i=0;i<4;++i) mk[j][i]+=accA[j][i]+accB[j][i];
    }
    // M1L: k-reduce over kg (tid bits 3,4), kg==0 lanes write both rows
    #pragma unroll
    for (int j=0;j<8;++j){
      float rA=sjA[j];
      rA += __shfl_xor(rA, 8, 64);
      rA += __shfl_xor(rA, 16, 64);
      sjA[j]=rA;
      float rB=sjB[j];
      rB += __shfl_xor(rB, 8, 64);
      rB += __shfl_xor(rB, 16, 64);
      sjB[j]=rB;
    }
    if (kg==0){
      const float inv16 = 1.f/16.f;
      size_t baseA = OFF_M1L + ((size_t)b*64 + pblkA*8 + lloc)*64 + c0;
      size_t baseB = OFF_M1L + ((size_t)b*64 + pblkB*8 + lloc)*64 + c0;
      *(float4*)&ws[baseA]   = make_float4(sjA[0]*inv16, sjA[1]*inv16, sjA[2]*inv16, sjA[3]*inv16);
      *(float4*)&ws[baseA+4] = make_float4(sjA[4]*inv16, sjA[5]*inv16, sjA[6]*inv16, sjA[7]*inv16);
      *(float4*)&ws[baseB]   = make_float4(sjB[0]*inv16, sjB[1]*inv16, sjB[2]*inv16, sjB[3]*inv16);
      *(float4*)&ws[baseB+4] = make_float4(sjB[4]*inv16, sjB[5]*inv16, sjB[6]*inv16, sjB[7]*inv16);
    }
    // mid-pair: all slot reads done -> write prefetched next pair
    if (pr==0){
      __syncthreads();
      int po = tid>>7, idx = tid&127;
      *(float4*)&sm[PD_X1D  + po*512 + idx*4] = n1;
      *(float4*)&sm[PD_X08D + po*512 + idx*4] = n8;
    }
  }
  __syncthreads();   // all GEMM/slot reads done -> overlay dead regions
  // M1K exchange: lloc-pair shfl, owner lanes write per-wave copies at
  // [0,4352) (dead W1). Writer stride 33 -> all 32 banks.
  #pragma unroll
  for (int j=0;j<8;++j){
    #pragma unroll
    for (int i=0;i<4;++i){
      float v = mk[j][i] + __shfl_xor(mk[j][i], 32, 64);
      if ((tid & 32)==0)
        sm[wv*1088 + (og*4+kg)*33 + i*8 + j] = v;
    }
  }
  // qsum exchange at [4384,6496) (dead Y0/Y1)
  {
    int pg = tid>>3;
    #pragma unroll
    for (int j=0;j<8;++j) sm[4384+(c0+j)*33+pg] = qsum[j];
  }
  __syncthreads();
  unsigned mko = h ? OFF_M1KB : OFF_M1K;
  float tsacc=0.f;
  #pragma unroll
  for (int r=0;r<4;++r){
    int e = tid + r*256;
    int k=e>>6, c=e&63;
    int a = ((c>>3)*4+(k>>2))*33 + (k&3)*8 + (c&7);
    float v = sm[a]+sm[1088+a]+sm[2176+a]+sm[3264+a];
    tsacc += v;
    ws[mko+(size_t)b*1024+e] = v*(1.f/64.f);
  }
  sm[6496 + (tid&63)*5 + wv] = tsacc;   // [6496,6816) dead X1d[0]
  __syncthreads();
  if (tid<64){
    float ts  = sm[6496+tid*5+0]+sm[6496+tid*5+1]+sm[6496+tid*5+2]+sm[6496+tid*5+3];
    float tss = 0.f;
    for (int g=0; g<32; ++g) tss += sm[4384+tid*33+g];
    int stripe = b & (NSTRIPE-1);
    atomicAdd(&ws[OFF_SUM1+stripe*64+tid], ts);
    atomicAdd(&ws[OFF_SSQ1+stripe*64+tid], tss);
  }
}

// K4-SMALL: fallback (round-4 proven): one block per b, LDS stride-33 MK RMW.
#define MK_OFF 8224
__global__ __launch_bounds__(256) void k_pass1(float* __restrict__ ws,
                                               const float* __restrict__ P11,
                                               const float* __restrict__ P40){
  __shared__ float sm[12576];
  int b=blockIdx.x, tid=threadIdx.x;
  int og=tid&7, pg=tid>>3, lloc=pg>>2, kg=pg&3, c0=og*8, wv=tid>>6;
  for (int t=tid;t<4096;t+=256){ int o=t>>6,c=t&63; sm[T_W1+lds_row(o)+c]=2.0f*P11[t]; }
  for (int t=tid;t<1024;t+=256){ int k=t>>6,c=t&63; sm[T_Y0+k*68+c]=ws[OFF_Y0+(size_t)b*1024+t]; }
  for (int t=tid;t<1024;t+=256) sm[T_Y1+t]=ws[OFF_Y1+(size_t)b*1024+t];
  for (int t=tid;t<512;t+=256){ int c=t&63,j=t>>6; sm[T_P4T0+j*64+c]=P40[c*8+j]; }
  if (tid<64){ sm[T_S0+tid]=ws[OFF_S0+tid]; sm[T_T0+tid]=ws[OFF_T0+tid]; }
  for (int t=tid;t<4352;t+=256) sm[MK_OFF+t]=0.f;
  float qsum[8];
  #pragma unroll
  for (int j=0;j<8;++j) qsum[j]=0.f;
  #pragma unroll 1
  for (int pblk=0;pblk<8;++pblk){
    __syncthreads();
    for (int t=tid;t<512;t+=256) sm[T_X1+t]=ws[OFF_X1+((size_t)b*64+pblk*8)*64+t];
    if (tid<64) sm[T_HB8+tid]=ws[OFF_HBL+((size_t)b*64+pblk*8)*8+tid];
    __syncthreads();
    for (int e=tid;e<512;e+=256){ int l=e>>6,c=e&63; float s=0.f;
      #pragma unroll
      for(int j=0;j<8;++j) s += sm[T_P4T0+j*64+c]*sm[T_HB8+l*8+j];
      sm[T_X08+e]=0.1f*s; }
    __syncthreads();
    float acc[8][4];
    {
      float xb[8];
      *(float4*)&xb[0] = *(const float4*)&sm[T_X1 + lloc*64 + c0];
      *(float4*)&xb[4] = *(const float4*)&sm[T_X1 + lloc*64 + c0 + 4];
      #pragma unroll
      for (int i=0;i<4;++i){
        int k=kg*4+i;
        float yb[8];
        *(float4*)&yb[0] = *(const float4*)&sm[T_Y1 + k*64 + c0];
        *(float4*)&yb[4] = *(const float4*)&sm[T_Y1 + k*64 + c0 + 4];
        #pragma unroll
        for (int j=0;j<8;++j) acc[j][i]=xb[j]+yb[j];
      }
    }
    #pragma unroll 4
    for (int c4=0;c4<16;++c4){
      float4 xr  = *(const float4*)&sm[T_X08 + lloc*64 + c4*4];
      float4 s0v = *(const float4*)&sm[T_S0 + c4*4];
      float4 t0v = *(const float4*)&sm[T_T0 + c4*4];
      float4 aa[4];
      #pragma unroll
      for (int i=0;i<4;++i){
        int k=kg*4+i;
        float4 yr = *(const float4*)&sm[T_Y0 + k*68 + c4*4];
        aa[i].x = s0v.x*relu_f(xr.x+yr.x)+t0v.x;
        aa[i].y = s0v.y*relu_f(xr.y+yr.y)+t0v.y;
        aa[i].z = s0v.z*relu_f(xr.z+yr.z)+t0v.z;
        aa[i].w = s0v.w*relu_f(xr.w+yr.w)+t0v.w;
      }
      #pragma unroll
      for (int j=0;j<8;++j){
        float4 w = *(const float4*)&sm[T_W1 + lds_row(c0+j) + c4*4];
        #pragma unroll
        for (int i=0;i<4;++i)
          acc[j][i] += w.x*aa[i].x + w.y*aa[i].y + w.z*aa[i].z + w.w*aa[i].w;
      }
    }
    #pragma unroll
    for (int j=0;j<8;++j)
      #pragma unroll
      for (int i=0;i<4;++i) acc[j][i] = relu_f(acc[j][i]);
    float sj[8];
    #pragma unroll
    for (int j=0;j<8;++j){
      sj[j]=acc[j][0]+acc[j][1]+acc[j][2]+acc[j][3];
      qsum[j]+=acc[j][0]*acc[j][0]+acc[j][1]*acc[j][1]+acc[j][2]*acc[j][2]+acc[j][3]*acc[j][3];
    }
    #pragma unroll
    for (int j=0;j<8;++j){
      float r=sj[j];
      r += __shfl_xor(r, 8, 64);
      r += __shfl_xor(r, 16, 64);
      sj[j]=r;
    }
    if (kg==0){
      const float inv16 = 1.f/16.f;
      float4 v0 = make_float4(sj[0]*inv16, sj[1]*inv16, sj[2]*inv16, sj[3]*inv16);
      float4 v1 = make_float4(sj[4]*inv16, sj[5]*inv16, sj[6]*inv16, sj[7]*inv16);
      size_t base = OFF_M1L + ((size_t)b*64 + pblk*8 + lloc)*64 + c0;
      *(float4*)&ws[base]   = v0;
      *(float4*)&ws[base+4] = v1;
    }
    #pragma unroll
    for (int j=0;j<8;++j){
      #pragma unroll
      for (int i=0;i<4;++i){
        float v = acc[j][i] + __shfl_xor(acc[j][i], 32, 64);
        if ((tid & 32)==0)
          sm[MK_OFF + wv*1088 + (og*4+kg)*33 + i*8 + j] += v;
      }
    }
  }
  __syncthreads();
  float tsacc=0.f;
  #pragma unroll
  for (int r=0;r<4;++r){
    int e = tid + r*256;
    int k=e>>6, c=e&63;
    int a = ((c>>3)*4+(k>>2))*33 + (k&3)*8 + (c&7);
    float v = sm[MK_OFF+a]+sm[MK_OFF+1088+a]+sm[MK_OFF+2176+a]+sm[MK_OFF+3264+a];
    tsacc += v;
    ws[OFF_M1K+(size_t)b*1024+e] = v*(1.f/64.f);
  }
  __syncthreads();
  sm[8224 + (tid&63)*5 + wv] = tsacc;
  #pragma unroll
  for (int j=0;j<8;++j) sm[8544+(c0+j)*33+pg] = qsum[j];
  __syncthreads();
  if (tid<64){
    float ts  = sm[8224+tid*5+0]+sm[8224+tid*5+1]+sm[8224+tid*5+2]+sm[8224+tid*5+3];
    float tss = 0.f;
    for (int g=0; g<32; ++g) tss += sm[8544+tid*33+g];
    int stripe = b & (NSTRIPE-1);
    atomicAdd(&ws[OFF_SUM1+stripe*64+tid], ts);
    atomicAdd(&ws[OFF_SSQ1+stripe*64+tid], tss);
  }
}

// K5: tiny per-b pass: X2/Y2 from raw M1L/M1K + BN1 (inlined). No atomics.
__global__ __launch_bounds__(256) void k_xy2s(float* __restrict__ ws,
                                              const float* __restrict__ P22,
                                              const float* __restrict__ P42,
                                              const float* __restrict__ g1,
                                              const float* __restrict__ b1,
                                              int two){
  __shared__ float mln[4352];   // [l][68] : s1*M1L+t1
  __shared__ float mkn[1088];   // [k][68] : s1*M1K+t1
  __shared__ float w2[512];     // [c*8+o2] = 2*P22[o2][c]
  __shared__ float p42s[64];    // [o2*8+j]
  __shared__ float hbl[512];    // [l*8+j]
  __shared__ float hbk[128];    // [k*8+j]
  __shared__ float s1l[64], t1l[64];
  int b = blockIdx.x, tid = threadIdx.x;
  bn_inline(ws, OFF_SUM1, g1, b1, tid, s1l, t1l);
  for (int t=tid;t<512;t+=256) w2[t] = 2.0f*P22[(t&7)*64 + (t>>3)];
  if (tid>=64 && tid<128) p42s[tid-64] = P42[tid-64];
  for (int t=tid;t<512;t+=256) hbl[t] = ws[OFF_HBL+(size_t)b*512+t];
  if (tid>=128 && tid<256 && tid-128<128) hbk[tid-128] = ws[OFF_HBK+(size_t)b*128+(tid-128)];
  __syncthreads();
  for (int t=tid;t<4096;t+=256){ int l=t>>6,c=t&63;
    mln[l*68+c] = s1l[c]*ws[OFF_M1L+(size_t)b*4096+t] + t1l[c]; }
  for (int t=tid;t<1024;t+=256){ int k=t>>6,c=t&63;
    float mv = ws[OFF_M1K+(size_t)b*1024+t];
    if (two) mv += ws[OFF_M1KB+(size_t)b*1024+t];
    mkn[k*68+c] = s1l[c]*mv + t1l[c]; }
  __syncthreads();
  for (int t=tid;t<512;t+=256){
    int l=t>>3, o2=t&7;
    float s=0.f;
    for (int c=0;c<64;++c) s += w2[c*8+o2]*mln[l*68+c];
    float s2=0.f;
    #pragma unroll
    for (int j=0;j<8;++j) s2 += p42s[o2*8+j]*hbl[l*8+j];
    ws[OFF_X2+(size_t)b*512+t] = s + 0.1f*s2;
  }
  if (tid<128){
    int k=tid>>3, o2=tid&7;
    float s=0.f;
    for (int c=0;c<64;++c) s += w2[c*8+o2]*mkn[k*68+c];
    float s2=0.f;
    #pragma unroll
    for (int j=0;j<8;++j) s2 += p42s[o2*8+j]*hbk[k*8+j];
    ws[OFF_Y2+(size_t)b*128+tid] = s + 0.1f*s2;
  }
}

// ---- shared epilogue (small path, 128 active threads; 133-stride T1c) ----
__device__ __forceinline__ void final_epilogue(const float* __restrict__ ws,
                                               float* sm, int b, int pblk, int tid,
                                               float* __restrict__ out,
                                               long long out_cap, int interleaved){
  if (tid < 128){
    int p = tid, k = p & 15, lglob = pblk*8 + (p>>4);
    float a2[8];
    {
      const float* xp = ws + OFF_X2 + ((size_t)b*64+lglob)*8;
      const float* yp = ws + OFF_Y2 + ((size_t)b*16+k)*8;
      float4 x0_ = *(const float4*)&xp[0];
      float4 x1_ = *(const float4*)&xp[4];
      float4 y0_ = *(const float4*)&yp[0];
      float4 y1_ = *(const float4*)&yp[4];
      a2[0]=x0_.x+y0_.x; a2[1]=x0_.y+y0_.y; a2[2]=x0_.z+y0_.z; a2[3]=x0_.w+y0_.w;
      a2[4]=x1_.x+y1_.x; a2[5]=x1_.y+y1_.y; a2[6]=x1_.z+y1_.z; a2[7]=x1_.w+y1_.w;
    }
    for (int c=0;c<64;++c){
      float tn = sm[9028+c]*sm[c*133 + (c>>3) + p] + sm[9092+c];   // s1*T1+t1
      #pragma unroll
      for (int o2=0;o2<8;++o2) a2[o2] += sm[8516+o2*64+c]*tn;
    }
    float nrm=0.f;
    #pragma unroll
    for (int o2=0;o2<8;++o2) nrm += a2[o2]*a2[o2];
    float inv = 1.0f/sqrtf(nrm);
    size_t pos = (size_t)b*PPP + lglob*KKK + k;
    if (interleaved){
      long long idx = (long long)pos*8;
      if (idx+8 <= out_cap){
        *(float4*)&out[idx]   = make_float4(a2[0]*inv, a2[4]*inv, a2[1]*inv, a2[5]*inv);
        *(float4*)&out[idx+4] = make_float4(a2[2]*inv, a2[6]*inv, a2[3]*inv, a2[7]*inv);
      }
    } else {
      long long idx = (long long)pos*4;
      if (idx+4 <= out_cap)
        *(float4*)&out[idx] = make_float4(a2[0]*inv, a2[1]*inv, a2[2]*inv, a2[3]*inv);
    }
  }
}

// K6-BIG: c-major T1S -> ds_write_b128 staging into stride-136 T1c
// (136*4B rows are 16B-aligned; epilogue reads lane-consecutive ->
// conflict-free). BN1 inlined; epilogue c-loop split across thread halves,
// combine via stride-9 LDS exchange on dead T1c.
__global__ __launch_bounds__(256) void k_final_big(const float* __restrict__ ws,
                                                   const float* __restrict__ P12,
                                                   const float* __restrict__ g1,
                                                   const float* __restrict__ b1,
                                                   float* __restrict__ out,
                                                   long long out_cap, int interleaved){
  __shared__ float sm[9344];   // T1c [0,8704) stride 136; W2l [8704,9216);
                               // s1 [9216,9280); t1 [9280,9344)
  int bid=blockIdx.x, b=bid>>3, pblk=bid&7, tid=threadIdx.x;
  for (int t=tid;t<512;t+=256) sm[8704+t] = 2.0f*P12[t];
  bn_inline(ws, OFF_SUM1, g1, b1, tid, sm+9216, sm+9280);
  {
    size_t base = OFF_T1S + ((size_t)b*8 + pblk)*8192;
    for (int t4=tid;t4<2048;t4+=256){
      float4 v = *(const float4*)&ws[base + (size_t)t4*4];
      int c = t4>>5, p4 = t4&31;
      *(float4*)&sm[c*136 + p4*4] = v;
    }
  }
  __syncthreads();
  int half = tid>>7, p = tid&127;
  int k = p & 15, lglob = pblk*8 + (p>>4);
  float a2[8];
  if (half==0){
    const float* xp = ws + OFF_X2 + ((size_t)b*64+lglob)*8;
    const float* yp = ws + OFF_Y2 + ((size_t)b*16+k)*8;
    float4 x0_ = *(const float4*)&xp[0];
    float4 x1_ = *(const float4*)&xp[4];
    float4 y0_ = *(const float4*)&yp[0];
    float4 y1_ = *(const float4*)&yp[4];
    a2[0]=x0_.x+y0_.x; a2[1]=x0_.y+y0_.y; a2[2]=x0_.z+y0_.z; a2[3]=x0_.w+y0_.w;
    a2[4]=x1_.x+y1_.x; a2[5]=x1_.y+y1_.y; a2[6]=x1_.z+y1_.z; a2[7]=x1_.w+y1_.w;
  } else {
    #pragma unroll
    for (int o2=0;o2<8;++o2) a2[o2]=0.f;
  }
  int cb = half*32;
  for (int cc=0;cc<32;++cc){
    int c = cb+cc;
    float tn = sm[9216+c]*sm[c*136 + p] + sm[9280+c];
    #pragma unroll
    for (int o2=0;o2<8;++o2) a2[o2] += sm[8704+o2*64+c]*tn;
  }
  __syncthreads();   // T1c reads done -> overlay exchange at [0,1152)
  if (half==1){
    #pragma unroll
    for (int o2=0;o2<8;++o2) sm[p*9+o2] = a2[o2];
  }
  __syncthreads();
  if (half==0){
    #pragma unroll
    for (int o2=0;o2<8;++o2) a2[o2] += sm[p*9+o2];
    float nrm=0.f;
    #pragma unroll
    for (int o2=0;o2<8;++o2) nrm += a2[o2]*a2[o2];
    float inv = 1.0f/sqrtf(nrm);
    size_t pos = (size_t)b*PPP + lglob*KKK + k;
    if (interleaved){
      long long idx = (long long)pos*8;
      if (idx+8 <= out_cap){
        *(float4*)&out[idx]   = make_float4(a2[0]*inv, a2[4]*inv, a2[1]*inv, a2[5]*inv);
        *(float4*)&out[idx+4] = make_float4(a2[2]*inv, a2[6]*inv, a2[3]*inv, a2[7]*inv);
      }
    } else {
      long long idx = (long long)pos*4;
      if (idx+4 <= out_cap)
        *(float4*)&out[idx] = make_float4(a2[0]*inv, a2[1]*inv, a2[2]*inv, a2[3]*inv);
    }
  }
}

// K6-SMALL: recompute T1 via t1_tile (round-4 proven fallback).
__global__ __launch_bounds__(256) void k_final(const float* __restrict__ ws,
                                               const float* __restrict__ P11,
                                               const float* __restrict__ P40,
                                               const float* __restrict__ P12,
                                               float* __restrict__ out,
                                               long long out_cap, int interleaved){
  __shared__ float sm[9156];
  int bid=blockIdx.x, b=bid>>3, pblk=bid&7, tid=threadIdx.x;
  int og=tid&7, pg=tid>>3, lloc=pg>>2, c0=og*8;
  for (int t=tid;t<512;t+=256) sm[8516+t] = 2.0f*P12[t];
  if (tid<64) sm[9028+tid]=ws[OFF_S1+tid];
  else if (tid<128) sm[9092+(tid-64)]=ws[OFF_T1+(tid-64)];
  float acc[8][4];
  t1_tile(sm, ws, P11, P40, b, pblk, tid, acc, og, pg, lloc, c0);
  __syncthreads();
  {
    int kg = pg&3;
    #pragma unroll
    for (int i=0;i<4;++i){
      int p = lloc*16 + kg*4 + i;
      #pragma unroll
      for (int j=0;j<8;++j) sm[(c0+j)*133 + og + p] = acc[j][i];
    }
  }
  __syncthreads();
  final_epilogue(ws, sm, b, pblk, tid, out, out_cap, interleaved);
}

extern "C" void kernel_launch(void* const* d_in, const int* in_sizes, int n_in,
                              void* d_out, int out_size, void* d_ws, size_t ws_size,
                              hipStream_t stream) {
  if (n_in < 15) return;
  if (in_sizes[0] != BRR*4096 || in_sizes[1] != BRR*4096) return;
  if (in_sizes[4] != 512)  return;   // P4_0 (64,8)
  if (in_sizes[7] != 4096) return;   // P1_1 (64,64)
  if (in_sizes[12] != 512) return;   // P1_2 (8,64)
  if (ws_size < (size_t)WS_FLOATS*4) return;   // clean fail, not a fault

  const float* Hr   = (const float*)d_in[0];
  const float* Hi   = (const float*)d_in[1];
  const float* P4_0 = (const float*)d_in[4];
  const float* g0   = (const float*)d_in[5];
  const float* b0   = (const float*)d_in[6];
  const float* P1_1 = (const float*)d_in[7];
  const float* P2_1 = (const float*)d_in[8];
  const float* P4_1 = (const float*)d_in[9];
  const float* g1   = (const float*)d_in[10];
  const float* b1   = (const float*)d_in[11];
  const float* P1_2 = (const float*)d_in[12];
  const float* P2_2 = (const float*)d_in[13];
  const float* P4_2 = (const float*)d_in[14];
  float* ws  = (float*)d_ws;
  float* out = (float*)d_out;
  int interleaved = (out_size >= 4194304) ? 1 : 0;
  int big = (ws_size >= (size_t)WS_BIG*4) ? 1 : 0;   // T1-spill path needs ~155 MiB

  k_zero<<<4, 256, 0, stream>>>((float4*)(ws + OFF_SUM0), 4096/4);
  k_prep<<<BRR, 256, 0, stream>>>(Hr, Hi, P4_0, ws);
  if (big){
    k_xy1<<<2560, 256, 0, stream>>>(ws, P2_1, P4_1, g0, b0);
    k_pass1f<<<BRR*2, 256, 0, stream>>>(ws, P1_1, g0, b0);
    k_xy2s<<<BRR, 256, 0, stream>>>(ws, P2_2, P4_2, g1, b1, 1);
    k_final_big<<<BRR*8, 256, 0, stream>>>(ws, P1_2, g1, b1, out,
                                           (long long)out_size, interleaved);
  } else {
    k_bn<<<1, 64, 0, stream>>>(ws, g0, b0, OFF_SUM0, OFF_S0);
    k_xy1<<<2560, 256, 0, stream>>>(ws, P2_1, P4_1, g0, b0);
    k_pass1<<<BRR, 256, 0, stream>>>(ws, P1_1, P4_0);
    k_bn<<<1, 64, 0, stream>>>(ws, g1, b1, OFF_SUM1, OFF_S1);
    k_xy2s<<<BRR, 256, 0, stream>>>(ws, P2_2, P4_2, g1, b1, 0);
    k_final<<<BRR*8, 256, 0, stream>>>(ws, P1_2 ? P1_1 : P1_1, P4_0, P1_2, out,
                                       (long long)out_size, interleaved);
  }
}

// Round 13
// 273.969 us; speedup vs baseline: 1.1123x; 1.1123x over previous
//
#include <hip/hip_runtime.h>
#include <math.h>

#define BRR 512
#define LLL 64
#define KKK 16
#define EEE 64
#define CC2 8
#define PPP 1024
#define BN_EPS 1e-5f
#define NSTRIPE 16

__device__ __forceinline__ float relu_f(float v){ return v>0.f?v:0.f; }
// Row-padded W1 layout: stride 68 + 4-float stagger per 8-row octet.
__device__ __forceinline__ int lds_row(int r){ return r*68 + (((r>>3)&7)<<2); }

// ---- d_ws float layout ----
#define OFF_HBL  0u          // [(b*64+l)*8+c2]            262144
#define OFF_HBK  262144u     // [(b*16+k)*8+c2]             65536
#define OFF_Y0   327680u     // [b*1024 + k*64+c]          524288
#define OFF_X1   851968u     // [(b*64+l)*64+c] M0L->X1   2097152
#define OFF_Y1   2949120u    // [b*1024 + k*64+o] M0K->Y1  524288
#define OFF_X2   3473408u    // [(b*64+l)*8+o2]            262144
#define OFF_Y2   3735552u    // [(b*16+k)*8+o2]             65536
#define OFF_M1L  3801088u    // pre-pass1: x0 (X08); post: raw k-mean of T1
#define OFF_M1K  5898240u    // [b*1024 + k*64+c] raw l-mean half0   524288
#define OFF_SUM0 6422528u
#define OFF_SSQ0 6423552u
#define OFF_SUM1 6424576u
#define OFF_SSQ1 6425600u
#define OFF_S0   6426624u
#define OFF_T0   6426688u
#define OFF_S1   6426752u
#define OFF_T1   6426816u
#define WS_FLOATS 6426880u   // 25,707,520 bytes (small/fallback footprint)
// ---- big-ws extension (only touched when ws_size >= WS_BIG*4) ----
#define OFF_M1KB 6426880u    // M1K half1 partial                    524288
#define OFF_T1S  6951168u    // raw T1 tiles [(b*8+pblk)*8192 + j*1024 + lane*4 + i]
#define WS_BIG   40505600u   // 162,022,400 bytes (~154.5 MiB)

// Inline BN0/BN1 finalize (redundant per block; same math as k_bn).
__device__ __forceinline__ void bn_inline(const float* __restrict__ ws,
                                          unsigned sumOff,
                                          const float* __restrict__ g_,
                                          const float* __restrict__ b_,
                                          int tid, float* sc_out, float* st_out){
  if (tid < 64){
    float s=0.f, ss=0.f;
    for (int i=0;i<NSTRIPE;++i){ s+=ws[sumOff+i*64+tid]; ss+=ws[sumOff+1024+i*64+tid]; }
    const float invN = 1.0f/((float)BRR*LLL*KKK);
    float mu=s*invN, var=ss*invN-mu*mu;
    float sc = g_[tid]/sqrtf(var+BN_EPS);
    sc_out[tid]=sc;
    st_out[tid]=b_[tid]-mu*sc;
  }
}

// ---------------------------------------------------------------------------
// K0: zero stat accumulators only (4096 floats).
__global__ void k_zero(float4* __restrict__ p, int n4){
  int t = blockIdx.x*256 + threadIdx.x;
  if (t < n4) p[t] = make_float4(0.f,0.f,0.f,0.f);
}

// K1: per-b prep. HbL,HbK,y0,M0K,M0L + BN0 channel sums. Also stores x0
// (=X08) into the pre-pass1-dead OFF_M1L region. float4 staging/stores (G13).
__global__ __launch_bounds__(256) void k_prep(const float* __restrict__ Hr,
                                              const float* __restrict__ Hi,
                                              const float* __restrict__ P40,
                                              float* __restrict__ ws){
  __shared__ float sm[9344];
  int b = blockIdx.x, tid = threadIdx.x;
  const float* hrg = Hr + (size_t)b*4096;
  const float* hig = Hi + (size_t)b*4096;
  for (int t4=tid;t4<1024;t4+=256){
    *(float4*)&sm[t4*4]      = *(const float4*)&hrg[t4*4];
    *(float4*)&sm[4096+t4*4] = *(const float4*)&hig[t4*4];
  }
  for (int t=tid;t<512;t+=256){ int c=t&63,j=t>>6; sm[8192+j*64+c]=P40[c*8+j]; }
  __syncthreads();
  for (int t=tid;t<512;t+=256){ int l=t>>3,c2=t&7;          // HbL [8704,9216)
    const float* src=sm+((c2<4)?0:4096); int u=c2&3;
    float s=0.f;
    #pragma unroll
    for(int k=0;k<16;++k) s+=src[(l*16+k)*4+u];
    sm[8704+t]=s*(1.f/16.f); }
  for (int t=tid;t<128;t+=256){ int k=t>>3,c2=t&7;          // HbK [9216,9344)
    const float* src=sm+((c2<4)?0:4096); int u=c2&3;
    float s=0.f;
    for(int l=0;l<64;++l) s+=src[(l*16+k)*4+u];
    sm[9216+t]=s*(1.f/64.f); }
  __syncthreads();
  for (int t=tid;t<1024;t+=256){ int k=t>>6,c=t&63; float s=0.f;   // y0 [4096,5120)
    #pragma unroll
    for(int j=0;j<8;++j) s+=sm[8192+j*64+c]*sm[9216+k*8+j];
    sm[4096+t]=0.1f*s; }
  for (int t=tid;t<4096;t+=256){ int l=t>>6,c=t&63; float s=0.f;   // x0 [0,4096)
    #pragma unroll
    for(int j=0;j<8;++j) s+=sm[8192+j*64+c]*sm[8704+l*8+j];
    sm[t]=0.1f*s; }
  __syncthreads();
  for (int t=tid;t<1024;t+=256){ int c=t&63; float yv=sm[4096+t]; float s=0.f;  // M0K [5120,6144)
    for(int l=0;l<64;++l) s+=relu_f(sm[l*64+c]+yv);
    sm[5120+t]=s*(1.f/64.f); }
  float ssum=0.f, ssq=0.f;                       // channel c = tid&63 (stride 256 preserves it)
  for (int t=tid;t<4096;t+=256){ int c=t&63; float xv=sm[t]; float s=0.f;
    #pragma unroll
    for(int k=0;k<16;++k){ float v=relu_f(xv+sm[4096+k*64+c]); s+=v; ssq+=v*v; }
    ssum+=s;
    ws[OFF_X1+(size_t)b*4096+t]=s*(1.f/16.f); }  // M0L
  __syncthreads();
  sm[6144+tid]=ssum; sm[6400+tid]=ssq;
  __syncthreads();
  if (tid<64){
    float ts =sm[6144+tid]+sm[6208+tid]+sm[6272+tid]+sm[6336+tid];
    float tss=sm[6400+tid]+sm[6464+tid]+sm[6528+tid]+sm[6592+tid];
    int stripe = b & (NSTRIPE-1);
    atomicAdd(&ws[OFF_SUM0+stripe*64+tid], ts);
    atomicAdd(&ws[OFF_SSQ0+stripe*64+tid], tss);
  }
  for (int t4=tid;t4<128;t4+=256)
    *(float4*)&ws[OFF_HBL+(size_t)b*512+t4*4] = *(const float4*)&sm[8704+t4*4];
  for (int t=tid;t<128;t+=256)  ws[OFF_HBK+(size_t)b*128+t]=sm[9216+t];
  for (int t4=tid;t4<256;t4+=256)
    *(float4*)&ws[OFF_Y0+(size_t)b*1024+t4*4] = *(const float4*)&sm[4096+t4*4];
  for (int t4=tid;t4<256;t4+=256)
    *(float4*)&ws[OFF_Y1+(size_t)b*1024+t4*4] = *(const float4*)&sm[5120+t4*4];   // M0K
  for (int t4=tid;t4<1024;t4+=256)
    *(float4*)&ws[OFF_M1L+(size_t)b*4096+t4*4] = *(const float4*)&sm[t4*4];       // x0
}

// K2: finalize BN -> s,t (small path only; big path inlines).
__global__ void k_bn(float* __restrict__ ws, const float* __restrict__ g_,
                     const float* __restrict__ b_, unsigned sumOff, unsigned outOff){
  int tid = threadIdx.x;
  bn_inline(ws, sumOff, g_, b_, tid, ws+outOff, ws+outOff+64);
}

// K3: X1/Y1 in place over M0L/M0K. BN0 inlined; coalesced float4 P21 staging
// into stride-65 transposed wt (writer 2-way = free, reader conflict-free).
__global__ __launch_bounds__(256) void k_xy1(float* __restrict__ ws,
                                             const float* __restrict__ P21,
                                             const float* __restrict__ P41,
                                             const float* __restrict__ g0,
                                             const float* __restrict__ b0){
  __shared__ float wt[4160], p41[512], mrow[1024], hbs[128], s0l[64], t0l[64];
  int bx = blockIdx.x, tid = threadIdx.x;
  for (int t4=tid;t4<1024;t4+=256){           // wt[c*65+o] = 2*P21[o*64+c]
    int o=t4>>4, c4=(t4&15)*4;
    float4 v = *(const float4*)&P21[o*64+c4];
    wt[(c4+0)*65+o]=2.f*v.x; wt[(c4+1)*65+o]=2.f*v.y;
    wt[(c4+2)*65+o]=2.f*v.z; wt[(c4+3)*65+o]=2.f*v.w;
  }
  for (int t=tid;t<512;t+=256)  p41[t] = P41[t];                        // [o*8+j]
  bn_inline(ws, OFF_SUM0, g0, b0, tid, s0l, t0l);
  bool isX = bx < 2048;
  int row0 = isX ? bx*16 : (bx-2048)*16;
  if (isX){
    for (int t4=tid;t4<256;t4+=256)
      *(float4*)&mrow[t4*4] = *(const float4*)&ws[OFF_X1+(size_t)row0*64+t4*4];
    if (tid<128) hbs[tid] = ws[OFF_HBL+(size_t)row0*8+tid];
  } else {
    for (int t4=tid;t4<256;t4+=256)
      *(float4*)&mrow[t4*4] = *(const float4*)&ws[OFF_Y1+(size_t)row0*64+t4*4];
    if (tid<128) hbs[tid] = ws[OFF_HBK+(size_t)row0*8+tid];
  }
  __syncthreads();
  for (int t=tid;t<1024;t+=256){ int c=t&63; mrow[t]=s0l[c]*mrow[t]+t0l[c]; }
  __syncthreads();
  int r4 = tid>>6, o = tid&63;
  #pragma unroll
  for (int rr=0;rr<4;++rr){
    int rl = rr*4 + r4;
    float s=0.f;
    for (int c=0;c<64;++c) s += wt[c*65+o]*mrow[rl*64+c];
    float s2=0.f;
    #pragma unroll
    for (int j=0;j<8;++j) s2 += p41[o*8+j]*hbs[rl*8+j];
    float res = s + 0.1f*s2;
    if (isX) ws[OFF_X1+(size_t)(row0+rl)*64+o] = res;
    else     ws[OFF_Y1+(size_t)(row0+rl)*64+o] = res;
  }
}

// ---- T1 tile LDS map (small-path t1_tile) ----
#define T_W1   0
#define T_X08  4384
#define T_Y0   4896
#define T_X1   5984
#define T_Y1   6496
#define T_S0   7520
#define T_T0   7584
#define T_P4T0 7648
#define T_HB8  8160
#define T_END  8224

// c4 loop unroll-4: full x16 unroll -> VGPR 256 tier (r3); unroll 4 -> 76 (r4).
__device__ void t1_tile(float* sm, const float* __restrict__ ws,
                        const float* __restrict__ P11, const float* __restrict__ P40,
                        int b, int pblk, int tid,
                        float acc[8][4], int og, int pg, int lloc, int c0){
  for (int t=tid;t<4096;t+=256){ int o=t>>6,c=t&63; sm[T_W1+lds_row(o)+c]=2.0f*P11[t]; }
  for (int t=tid;t<1024;t+=256){ int k=t>>6,c=t&63; sm[T_Y0+k*68+c]=ws[OFF_Y0+(size_t)b*1024+t]; }
  for (int t=tid;t<512;t+=256)  sm[T_X1+t]=ws[OFF_X1+((size_t)b*64+pblk*8)*64+t];
  for (int t=tid;t<1024;t+=256) sm[T_Y1+t]=ws[OFF_Y1+(size_t)b*1024+t];
  for (int t=tid;t<512;t+=256){ int c=t&63,j=t>>6; sm[T_P4T0+j*64+c]=P40[c*8+j]; }
  if (tid<64){ sm[T_S0+tid]=ws[OFF_S0+tid]; sm[T_T0+tid]=ws[OFF_T0+tid]; }
  else if (tid<128){ int t2=tid-64; sm[T_HB8+t2]=ws[OFF_HBL+((size_t)b*64+pblk*8)*8+t2]; }
  __syncthreads();
  for (int e=tid;e<512;e+=256){ int l=e>>6,c=e&63; float s=0.f;
    #pragma unroll
    for(int j=0;j<8;++j) s += sm[T_P4T0+j*64+c]*sm[T_HB8+l*8+j];
    sm[T_X08+e]=0.1f*s; }
  __syncthreads();
  {
    float xb[8];
    *(float4*)&xb[0] = *(const float4*)&sm[T_X1 + lloc*64 + c0];
    *(float4*)&xb[4] = *(const float4*)&sm[T_X1 + lloc*64 + c0 + 4];
    #pragma unroll
    for (int i=0;i<4;++i){
      int k=(pg&3)*4+i;
      float yb[8];
      *(float4*)&yb[0] = *(const float4*)&sm[T_Y1 + k*64 + c0];
      *(float4*)&yb[4] = *(const float4*)&sm[T_Y1 + k*64 + c0 + 4];
      #pragma unroll
      for (int j=0;j<8;++j) acc[j][i]=xb[j]+yb[j];
    }
  }
  #pragma unroll 4
  for (int c4=0;c4<16;++c4){
    float4 xr  = *(const float4*)&sm[T_X08 + lloc*64 + c4*4];
    float4 s0v = *(const float4*)&sm[T_S0 + c4*4];
    float4 t0v = *(const float4*)&sm[T_T0 + c4*4];
    float4 aa[4];
    #pragma unroll
    for (int i=0;i<4;++i){
      int k=(pg&3)*4+i;
      float4 yr = *(const float4*)&sm[T_Y0 + k*68 + c4*4];
      aa[i].x = s0v.x*relu_f(xr.x+yr.x)+t0v.x;
      aa[i].y = s0v.y*relu_f(xr.y+yr.y)+t0v.y;
      aa[i].z = s0v.z*relu_f(xr.z+yr.z)+t0v.z;
      aa[i].w = s0v.w*relu_f(xr.w+yr.w)+t0v.w;
    }
    #pragma unroll
    for (int j=0;j<8;++j){
      float4 w = *(const float4*)&sm[T_W1 + lds_row(c0+j) + c4*4];
      #pragma unroll
      for (int i=0;i<4;++i)
        acc[j][i] += w.x*aa[i].x + w.y*aa[i].y + w.z*aa[i].z + w.w*aa[i].w;
    }
  }
  #pragma unroll
  for (int j=0;j<8;++j)
    #pragma unroll
    for (int i=0;i<4;++i) acc[j][i] = relu_f(acc[j][i]);
}

// ---- pass1f LDS map (big path, pair-slot X1/X08) ----
#define PD_W1   0      // [0,4384)  padded W (lds_row)
#define PD_Y0   4384   // [4384,5472)  16 x 68
#define PD_Y1   5472   // [5472,6496)
#define PD_X1D  6496   // [6496,7520)  2 slots x 512 (pblk pair)
#define PD_X08D 7520   // [7520,8544)  2 slots x 512
#define PD_CT   8544   // [8544,8608)
#define PD_S0   8608   // [8608,8672)
#define PD_T0   8672   // [8672,8736)
#define PD_TOT  8736   // 34.9 KB -> 4 blocks/CU

// K4-BIG v6 (r10/r11 proven, ~95-98us, VGPR 124): 2-pblk-per-thread blocking;
// BN0 inlined; ROW-MAJOR T1S store (tid*4 + j*1024 — folds to one base +
// constant immediates; the r12 c-major variant added address regs -> VGPR
// 132 crossed the 128 tier -> 40us regression. Do NOT touch this store.)
__global__ __launch_bounds__(256) void k_pass1f(float* __restrict__ ws,
                                                const float* __restrict__ P11,
                                                const float* __restrict__ g0,
                                                const float* __restrict__ b0){
  __shared__ float sm[PD_TOT];
  int b = blockIdx.x >> 1, h = blockIdx.x & 1;
  int pb0 = h*4;
  int tid=threadIdx.x;
  int og=tid&7, kg=(tid>>3)&3, lloc=tid>>5, c0=og*8, wv=tid>>6;
  // stage W (2*P11, float4), Y0 (stride 68), Y1; BN0 finalize inline
  for (int t4=tid;t4<1024;t4+=256){ int o=t4>>4,c=(t4&15)*4;
    float4 v = *(const float4*)&P11[o*64+c];
    v.x*=2.f; v.y*=2.f; v.z*=2.f; v.w*=2.f;
    *(float4*)&sm[PD_W1+lds_row(o)+c]=v; }
  for (int t4=tid;t4<256;t4+=256){
    float4 v = *(const float4*)&ws[OFF_Y0+(size_t)b*1024+t4*4];
    *(float4*)&sm[PD_Y0+(t4>>4)*68+((t4&15)*4)]=v; }
  for (int t4=tid;t4<256;t4+=256)
    *(float4*)&sm[PD_Y1+t4*4] = *(const float4*)&ws[OFF_Y1+(size_t)b*1024+t4*4];
  bn_inline(ws, OFF_SUM0, g0, b0, tid, sm+PD_S0, sm+PD_T0);
  // prologue: slots <- pair0 (pb0, pb0+1).
  {
    int po = tid>>7, idx = tid&127;
    float4 v1 = *(const float4*)&ws[OFF_X1 +((size_t)b*64+(pb0+po)*8)*64 + (size_t)idx*4];
    float4 v8 = *(const float4*)&ws[OFF_M1L+((size_t)b*64+(pb0+po)*8)*64 + (size_t)idx*4];
    *(float4*)&sm[PD_X1D  + po*512 + idx*4] = v1;
    *(float4*)&sm[PD_X08D + po*512 + idx*4] = v8;
  }
  __syncthreads();
  if (tid<64){                       // ct[o] from UNSCALED W
    float ct=0.f;
    for (int c=0;c<64;++c) ct += sm[PD_W1+lds_row(tid)+c]*sm[PD_T0+c];
    sm[PD_CT+tid]=ct;
  }
  __syncthreads();
  for (int t4=tid;t4<1024;t4+=256){ int o=t4>>4,c=(t4&15)*4;
    float4 w = *(float4*)&sm[PD_W1+lds_row(o)+c];
    float4 s = *(const float4*)&sm[PD_S0+c];
    w.x*=s.x; w.y*=s.y; w.z*=s.z; w.w*=s.w;
    *(float4*)&sm[PD_W1+lds_row(o)+c]=w; }
  float qsum[8], mk[8][4];
  #pragma unroll
  for (int j=0;j<8;++j){ qsum[j]=0.f;
    #pragma unroll
    for (int i=0;i<4;++i) mk[j][i]=0.f; }
  #pragma unroll 1
  for (int pr=0;pr<2;++pr){
    int pblkA = pb0 + 2*pr, pblkB = pblkA + 1;
    __syncthreads();   // slots ready (prologue / prev mid-pair write); W-scale done
    float4 n1, n8;     // prefetch next pair into regs (T14 split)
    if (pr==0){
      int po = tid>>7, idx = tid&127, pn = pb0 + 2 + po;
      n1 = *(const float4*)&ws[OFF_X1 +((size_t)b*64+pn*8)*64 + (size_t)idx*4];
      n8 = *(const float4*)&ws[OFF_M1L+((size_t)b*64+pn*8)*64 + (size_t)idx*4];
    }
    float accA[8][4], accB[8][4];
    {
      float xbA[8], xbB[8], ctv[8];
      *(float4*)&xbA[0] = *(const float4*)&sm[PD_X1D       + lloc*64 + c0];
      *(float4*)&xbA[4] = *(const float4*)&sm[PD_X1D       + lloc*64 + c0 + 4];
      *(float4*)&xbB[0] = *(const float4*)&sm[PD_X1D + 512 + lloc*64 + c0];
      *(float4*)&xbB[4] = *(const float4*)&sm[PD_X1D + 512 + lloc*64 + c0 + 4];
      *(float4*)&ctv[0] = *(const float4*)&sm[PD_CT + c0];
      *(float4*)&ctv[4] = *(const float4*)&sm[PD_CT + c0 + 4];
      #pragma unroll
      for (int i=0;i<4;++i){
        int k=kg*4+i;
        float yb[8];
        *(float4*)&yb[0] = *(const float4*)&sm[PD_Y1 + k*64 + c0];
        *(float4*)&yb[4] = *(const float4*)&sm[PD_Y1 + k*64 + c0 + 4];
        #pragma unroll
        for (int j=0;j<8;++j){
          float base = yb[j]+ctv[j];
          accA[j][i]=xbA[j]+base;
          accB[j][i]=xbB[j]+base;
        }
      }
    }
    #pragma unroll 2
    for (int c4=0;c4<16;++c4){
      float4 xrA = *(const float4*)&sm[PD_X08D       + lloc*64 + c4*4];
      float4 xrB = *(const float4*)&sm[PD_X08D + 512 + lloc*64 + c4*4];
      float4 aaA[4], aaB[4];
      #pragma unroll
      for (int i=0;i<4;++i){
        int k=kg*4+i;
        float4 yr = *(const float4*)&sm[PD_Y0 + k*68 + c4*4];
        aaA[i].x = relu_f(xrA.x+yr.x); aaB[i].x = relu_f(xrB.x+yr.x);
        aaA[i].y = relu_f(xrA.y+yr.y); aaB[i].y = relu_f(xrB.y+yr.y);
        aaA[i].z = relu_f(xrA.z+yr.z); aaB[i].z = relu_f(xrB.z+yr.z);
        aaA[i].w = relu_f(xrA.w+yr.w); aaB[i].w = relu_f(xrB.w+yr.w);
      }
      #pragma unroll
      for (int j=0;j<8;++j){
        float4 w = *(const float4*)&sm[PD_W1 + lds_row(c0+j) + c4*4];
        #pragma unroll
        for (int i=0;i<4;++i){
          accA[j][i] += w.x*aaA[i].x + w.y*aaA[i].y + w.z*aaA[i].z + w.w*aaA[i].w;
          accB[j][i] += w.x*aaB[i].x + w.y*aaB[i].y + w.z*aaB[i].z + w.w*aaB[i].w;
        }
      }
    }
    #pragma unroll
    for (int j=0;j<8;++j)
      #pragma unroll
      for (int i=0;i<4;++i){
        accA[j][i] = relu_f(accA[j][i]);
        accB[j][i] = relu_f(accB[j][i]);
      }
    // ---- raw-T1 spill (coalesced float4; row-major [j][tid][i]) ----
    {
      size_t tbA = OFF_T1S + ((size_t)b*8 + pblkA)*8192 + (size_t)tid*4;
      size_t tbB = OFF_T1S + ((size_t)b*8 + pblkB)*8192 + (size_t)tid*4;
      #pragma unroll
      for (int j=0;j<8;++j){
        *(float4*)&ws[tbA + j*1024] =
          make_float4(accA[j][0],accA[j][1],accA[j][2],accA[j][3]);
        *(float4*)&ws[tbB + j*1024] =
          make_float4(accB[j][0],accB[j][1],accB[j][2],accB[j][3]);
      }
    }
    // ---- fold into running register reductions (both tiles) ----
    float sjA[8], sjB[8];
    #pragma unroll
    for (int j=0;j<8;++j){
      sjA[j]=accA[j][0]+accA[j][1]+accA[j][2]+accA[j][3];
      sjB[j]=accB[j][0]+accB[j][1]+accB[j][2]+accB[j][3];
      qsum[j]+=accA[j][0]*accA[j][0]+accA[j][1]*accA[j][1]+accA[j][2]*accA[j][2]+accA[j][3]*accA[j][3];
      qsum[j]+=accB[j][0]*accB[j][0]+accB[j][1]*accB[j][1]+accB[j][2]*accB[j][2]+accB[j][3]*accB[j][3];
      #pragma unroll
      for (int i=0;i<4;++i) mk[j][i]+=accA[j][i]+accB[j][i];
    }
    // M1L: k-reduce over kg (tid bits 3,4), kg==0 lanes write both rows
    #pragma unroll
    for (int j=0;j<8;++j){
      float rA=sjA[j];
      rA += __shfl_xor(rA, 8, 64);
      rA += __shfl_xor(rA, 16, 64);
      sjA[j]=rA;
      float rB=sjB[j];
      rB += __shfl_xor(rB, 8, 64);
      rB += __shfl_xor(rB, 16, 64);
      sjB[j]=rB;
    }
    if (kg==0){
      const float inv16 = 1.f/16.f;
      size_t baseA = OFF_M1L + ((size_t)b*64 + pblkA*8 + lloc)*64 + c0;
      size_t baseB = OFF_M1L + ((size_t)b*64 + pblkB*8 + lloc)*64 + c0;
      *(float4*)&ws[baseA]   = make_float4(sjA[0]*inv16, sjA[1]*inv16, sjA[2]*inv16, sjA[3]*inv16);
      *(float4*)&ws[baseA+4] = make_float4(sjA[4]*inv16, sjA[5]*inv16, sjA[6]*inv16, sjA[7]*inv16);
      *(float4*)&ws[baseB]   = make_float4(sjB[0]*inv16, sjB[1]*inv16, sjB[2]*inv16, sjB[3]*inv16);
      *(float4*)&ws[baseB+4] = make_float4(sjB[4]*inv16, sjB[5]*inv16, sjB[6]*inv16, sjB[7]*inv16);
    }
    // mid-pair: all slot reads done -> write prefetched next pair
    if (pr==0){
      __syncthreads();
      int po = tid>>7, idx = tid&127;
      *(float4*)&sm[PD_X1D  + po*512 + idx*4] = n1;
      *(float4*)&sm[PD_X08D + po*512 + idx*4] = n8;
    }
  }
  __syncthreads();   // all GEMM/slot reads done -> overlay dead regions
  // M1K exchange: lloc-pair shfl, owner lanes write per-wave copies at
  // [0,4352) (dead W1). Writer stride 33 -> all 32 banks.
  #pragma unroll
  for (int j=0;j<8;++j){
    #pragma unroll
    for (int i=0;i<4;++i){
      float v = mk[j][i] + __shfl_xor(mk[j][i], 32, 64);
      if ((tid & 32)==0)
        sm[wv*1088 + (og*4+kg)*33 + i*8 + j] = v;
    }
  }
  // qsum exchange at [4384,6496) (dead Y0/Y1)
  {
    int pg = tid>>3;
    #pragma unroll
    for (int j=0;j<8;++j) sm[4384+(c0+j)*33+pg] = qsum[j];
  }
  __syncthreads();
  unsigned mko = h ? OFF_M1KB : OFF_M1K;
  float tsacc=0.f;
  #pragma unroll
  for (int r=0;r<4;++r){
    int e = tid + r*256;
    int k=e>>6, c=e&63;
    int a = ((c>>3)*4+(k>>2))*33 + (k&3)*8 + (c&7);
    float v = sm[a]+sm[1088+a]+sm[2176+a]+sm[3264+a];
    tsacc += v;
    ws[mko+(size_t)b*1024+e] = v*(1.f/64.f);
  }
  sm[6496 + (tid&63)*5 + wv] = tsacc;   // [6496,6816) dead X1d[0]
  __syncthreads();
  if (tid<64){
    float ts  = sm[6496+tid*5+0]+sm[6496+tid*5+1]+sm[6496+tid*5+2]+sm[6496+tid*5+3];
    float tss = 0.f;
    for (int g=0; g<32; ++g) tss += sm[4384+tid*33+g];
    int stripe = b & (NSTRIPE-1);
    atomicAdd(&ws[OFF_SUM1+stripe*64+tid], ts);
    atomicAdd(&ws[OFF_SSQ1+stripe*64+tid], tss);
  }
}

// K4-SMALL: fallback (round-4 proven): one block per b, LDS stride-33 MK RMW.
#define MK_OFF 8224
__global__ __launch_bounds__(256) void k_pass1(float* __restrict__ ws,
                                               const float* __restrict__ P11,
                                               const float* __restrict__ P40){
  __shared__ float sm[12576];
  int b=blockIdx.x, tid=threadIdx.x;
  int og=tid&7, pg=tid>>3, lloc=pg>>2, kg=pg&3, c0=og*8, wv=tid>>6;
  for (int t=tid;t<4096;t+=256){ int o=t>>6,c=t&63; sm[T_W1+lds_row(o)+c]=2.0f*P11[t]; }
  for (int t=tid;t<1024;t+=256){ int k=t>>6,c=t&63; sm[T_Y0+k*68+c]=ws[OFF_Y0+(size_t)b*1024+t]; }
  for (int t=tid;t<1024;t+=256) sm[T_Y1+t]=ws[OFF_Y1+(size_t)b*1024+t];
  for (int t=tid;t<512;t+=256){ int c=t&63,j=t>>6; sm[T_P4T0+j*64+c]=P40[c*8+j]; }
  if (tid<64){ sm[T_S0+tid]=ws[OFF_S0+tid]; sm[T_T0+tid]=ws[OFF_T0+tid]; }
  for (int t=tid;t<4352;t+=256) sm[MK_OFF+t]=0.f;
  float qsum[8];
  #pragma unroll
  for (int j=0;j<8;++j) qsum[j]=0.f;
  #pragma unroll 1
  for (int pblk=0;pblk<8;++pblk){
    __syncthreads();
    for (int t=tid;t<512;t+=256) sm[T_X1+t]=ws[OFF_X1+((size_t)b*64+pblk*8)*64+t];
    if (tid<64) sm[T_HB8+tid]=ws[OFF_HBL+((size_t)b*64+pblk*8)*8+tid];
    __syncthreads();
    for (int e=tid;e<512;e+=256){ int l=e>>6,c=e&63; float s=0.f;
      #pragma unroll
      for(int j=0;j<8;++j) s += sm[T_P4T0+j*64+c]*sm[T_HB8+l*8+j];
      sm[T_X08+e]=0.1f*s; }
    __syncthreads();
    float acc[8][4];
    {
      float xb[8];
      *(float4*)&xb[0] = *(const float4*)&sm[T_X1 + lloc*64 + c0];
      *(float4*)&xb[4] = *(const float4*)&sm[T_X1 + lloc*64 + c0 + 4];
      #pragma unroll
      for (int i=0;i<4;++i){
        int k=kg*4+i;
        float yb[8];
        *(float4*)&yb[0] = *(const float4*)&sm[T_Y1 + k*64 + c0];
        *(float4*)&yb[4] = *(const float4*)&sm[T_Y1 + k*64 + c0 + 4];
        #pragma unroll
        for (int j=0;j<8;++j) acc[j][i]=xb[j]+yb[j];
      }
    }
    #pragma unroll 4
    for (int c4=0;c4<16;++c4){
      float4 xr  = *(const float4*)&sm[T_X08 + lloc*64 + c4*4];
      float4 s0v = *(const float4*)&sm[T_S0 + c4*4];
      float4 t0v = *(const float4*)&sm[T_T0 + c4*4];
      float4 aa[4];
      #pragma unroll
      for (int i=0;i<4;++i){
        int k=kg*4+i;
        float4 yr = *(const float4*)&sm[T_Y0 + k*68 + c4*4];
        aa[i].x = s0v.x*relu_f(xr.x+yr.x)+t0v.x;
        aa[i].y = s0v.y*relu_f(xr.y+yr.y)+t0v.y;
        aa[i].z = s0v.z*relu_f(xr.z+yr.z)+t0v.z;
        aa[i].w = s0v.w*relu_f(xr.w+yr.w)+t0v.w;
      }
      #pragma unroll
      for (int j=0;j<8;++j){
        float4 w = *(const float4*)&sm[T_W1 + lds_row(c0+j) + c4*4];
        #pragma unroll
        for (int i=0;i<4;++i)
          acc[j][i] += w.x*aa[i].x + w.y*aa[i].y + w.z*aa[i].z + w.w*aa[i].w;
      }
    }
    #pragma unroll
    for (int j=0;j<8;++j)
      #pragma unroll
      for (int i=0;i<4;++i) acc[j][i] = relu_f(acc[j][i]);
    float sj[8];
    #pragma unroll
    for (int j=0;j<8;++j){
      sj[j]=acc[j][0]+acc[j][1]+acc[j][2]+acc[j][3];
      qsum[j]+=acc[j][0]*acc[j][0]+acc[j][1]*acc[j][1]+acc[j][2]*acc[j][2]+acc[j][3]*acc[j][3];
    }
    #pragma unroll
    for (int j=0;j<8;++j){
      float r=sj[j];
      r += __shfl_xor(r, 8, 64);
      r += __shfl_xor(r, 16, 64);
      sj[j]=r;
    }
    if (kg==0){
      const float inv16 = 1.f/16.f;
      float4 v0 = make_float4(sj[0]*inv16, sj[1]*inv16, sj[2]*inv16, sj[3]*inv16);
      float4 v1 = make_float4(sj[4]*inv16, sj[5]*inv16, sj[6]*inv16, sj[7]*inv16);
      size_t base = OFF_M1L + ((size_t)b*64 + pblk*8 + lloc)*64 + c0;
      *(float4*)&ws[base]   = v0;
      *(float4*)&ws[base+4] = v1;
    }
    #pragma unroll
    for (int j=0;j<8;++j){
      #pragma unroll
      for (int i=0;i<4;++i){
        float v = acc[j][i] + __shfl_xor(acc[j][i], 32, 64);
        if ((tid & 32)==0)
          sm[MK_OFF + wv*1088 + (og*4+kg)*33 + i*8 + j] += v;
      }
    }
  }
  __syncthreads();
  float tsacc=0.f;
  #pragma unroll
  for (int r=0;r<4;++r){
    int e = tid + r*256;
    int k=e>>6, c=e&63;
    int a = ((c>>3)*4+(k>>2))*33 + (k&3)*8 + (c&7);
    float v = sm[MK_OFF+a]+sm[MK_OFF+1088+a]+sm[MK_OFF+2176+a]+sm[MK_OFF+3264+a];
    tsacc += v;
    ws[OFF_M1K+(size_t)b*1024+e] = v*(1.f/64.f);
  }
  __syncthreads();
  sm[8224 + (tid&63)*5 + wv] = tsacc;
  #pragma unroll
  for (int j=0;j<8;++j) sm[8544+(c0+j)*33+pg] = qsum[j];
  __syncthreads();
  if (tid<64){
    float ts  = sm[8224+tid*5+0]+sm[8224+tid*5+1]+sm[8224+tid*5+2]+sm[8224+tid*5+3];
    float tss = 0.f;
    for (int g=0; g<32; ++g) tss += sm[8544+tid*33+g];
    int stripe = b & (NSTRIPE-1);
    atomicAdd(&ws[OFF_SUM1+stripe*64+tid], ts);
    atomicAdd(&ws[OFF_SSQ1+stripe*64+tid], tss);
  }
}

// K5: tiny per-b pass: X2/Y2 from raw M1L/M1K + BN1 (inlined). No atomics.
__global__ __launch_bounds__(256) void k_xy2s(float* __restrict__ ws,
                                              const float* __restrict__ P22,
                                              const float* __restrict__ P42,
                                              const float* __restrict__ g1,
                                              const float* __restrict__ b1,
                                              int two){
  __shared__ float mln[4352];   // [l][68] : s1*M1L+t1
  __shared__ float mkn[1088];   // [k][68] : s1*M1K+t1
  __shared__ float w2[512];     // [c*8+o2] = 2*P22[o2][c]
  __shared__ float p42s[64];    // [o2*8+j]
  __shared__ float hbl[512];    // [l*8+j]
  __shared__ float hbk[128];    // [k*8+j]
  __shared__ float s1l[64], t1l[64];
  int b = blockIdx.x, tid = threadIdx.x;
  bn_inline(ws, OFF_SUM1, g1, b1, tid, s1l, t1l);
  for (int t=tid;t<512;t+=256) w2[t] = 2.0f*P22[(t&7)*64 + (t>>3)];
  if (tid>=64 && tid<128) p42s[tid-64] = P42[tid-64];
  for (int t=tid;t<512;t+=256) hbl[t] = ws[OFF_HBL+(size_t)b*512+t];
  if (tid>=128 && tid<256 && tid-128<128) hbk[tid-128] = ws[OFF_HBK+(size_t)b*128+(tid-128)];
  __syncthreads();
  for (int t=tid;t<4096;t+=256){ int l=t>>6,c=t&63;
    mln[l*68+c] = s1l[c]*ws[OFF_M1L+(size_t)b*4096+t] + t1l[c]; }
  for (int t=tid;t<1024;t+=256){ int k=t>>6,c=t&63;
    float mv = ws[OFF_M1K+(size_t)b*1024+t];
    if (two) mv += ws[OFF_M1KB+(size_t)b*1024+t];
    mkn[k*68+c] = s1l[c]*mv + t1l[c]; }
  __syncthreads();
  for (int t=tid;t<512;t+=256){
    int l=t>>3, o2=t&7;
    float s=0.f;
    for (int c=0;c<64;++c) s += w2[c*8+o2]*mln[l*68+c];
    float s2=0.f;
    #pragma unroll
    for (int j=0;j<8;++j) s2 += p42s[o2*8+j]*hbl[l*8+j];
    ws[OFF_X2+(size_t)b*512+t] = s + 0.1f*s2;
  }
  if (tid<128){
    int k=tid>>3, o2=tid&7;
    float s=0.f;
    for (int c=0;c<64;++c) s += w2[c*8+o2]*mkn[k*68+c];
    float s2=0.f;
    #pragma unroll
    for (int j=0;j<8;++j) s2 += p42s[o2*8+j]*hbk[k*8+j];
    ws[OFF_Y2+(size_t)b*128+tid] = s + 0.1f*s2;
  }
}

// ---- shared epilogue (small path, 128 active threads; 133-stride T1c) ----
__device__ __forceinline__ void final_epilogue(const float* __restrict__ ws,
                                               float* sm, int b, int pblk, int tid,
                                               float* __restrict__ out,
                                               long long out_cap, int interleaved){
  if (tid < 128){
    int p = tid, k = p & 15, lglob = pblk*8 + (p>>4);
    float a2[8];
    {
      const float* xp = ws + OFF_X2 + ((size_t)b*64+lglob)*8;
      const float* yp = ws + OFF_Y2 + ((size_t)b*16+k)*8;
      float4 x0_ = *(const float4*)&xp[0];
      float4 x1_ = *(const float4*)&xp[4];
      float4 y0_ = *(const float4*)&yp[0];
      float4 y1_ = *(const float4*)&yp[4];
      a2[0]=x0_.x+y0_.x; a2[1]=x0_.y+y0_.y; a2[2]=x0_.z+y0_.z; a2[3]=x0_.w+y0_.w;
      a2[4]=x1_.x+y1_.x; a2[5]=x1_.y+y1_.y; a2[6]=x1_.z+y1_.z; a2[7]=x1_.w+y1_.w;
    }
    for (int c=0;c<64;++c){
      float tn = sm[9028+c]*sm[c*133 + (c>>3) + p] + sm[9092+c];   // s1*T1+t1
      #pragma unroll
      for (int o2=0;o2<8;++o2) a2[o2] += sm[8516+o2*64+c]*tn;
    }
    float nrm=0.f;
    #pragma unroll
    for (int o2=0;o2<8;++o2) nrm += a2[o2]*a2[o2];
    float inv = 1.0f/sqrtf(nrm);
    size_t pos = (size_t)b*PPP + lglob*KKK + k;
    if (interleaved){
      long long idx = (long long)pos*8;
      if (idx+8 <= out_cap){
        *(float4*)&out[idx]   = make_float4(a2[0]*inv, a2[4]*inv, a2[1]*inv, a2[5]*inv);
        *(float4*)&out[idx+4] = make_float4(a2[2]*inv, a2[6]*inv, a2[3]*inv, a2[7]*inv);
      }
    } else {
      long long idx = (long long)pos*4;
      if (idx+4 <= out_cap)
        *(float4*)&out[idx] = make_float4(a2[0]*inv, a2[1]*inv, a2[2]*inv, a2[3]*inv);
    }
  }
}

// K6-BIG: stream stored raw T1 (row-major) -> T1c LDS; BN1 inlined; epilogue
// c-loop split across thread halves, combine via stride-9 LDS exchange.
__global__ __launch_bounds__(256) void k_final_big(const float* __restrict__ ws,
                                                   const float* __restrict__ P12,
                                                   const float* __restrict__ g1,
                                                   const float* __restrict__ b1,
                                                   float* __restrict__ out,
                                                   long long out_cap, int interleaved){
  __shared__ float sm[9156];
  int bid=blockIdx.x, b=bid>>3, pblk=bid&7, tid=threadIdx.x;
  for (int t=tid;t<512;t+=256) sm[8516+t] = 2.0f*P12[t];
  bn_inline(ws, OFF_SUM1, g1, b1, tid, sm+9028, sm+9092);
  {
    size_t base = OFF_T1S + ((size_t)b*8 + pblk)*8192;
    for (int t4=tid;t4<2048;t4+=256){
      float4 v = *(const float4*)&ws[base + (size_t)t4*4];
      int j = t4>>8, lane = t4&255;
      int c = (lane&7)*8 + j;
      int pb = (lane>>5)*16 + ((lane>>3)&3)*4;
      int o = c*133 + (c>>3) + pb;
      sm[o+0]=v.x; sm[o+1]=v.y; sm[o+2]=v.z; sm[o+3]=v.w;
    }
  }
  __syncthreads();
  int half = tid>>7, p = tid&127;
  int k = p & 15, lglob = pblk*8 + (p>>4);
  float a2[8];
  if (half==0){
    const float* xp = ws + OFF_X2 + ((size_t)b*64+lglob)*8;
    const float* yp = ws + OFF_Y2 + ((size_t)b*16+k)*8;
    float4 x0_ = *(const float4*)&xp[0];
    float4 x1_ = *(const float4*)&xp[4];
    float4 y0_ = *(const float4*)&yp[0];
    float4 y1_ = *(const float4*)&yp[4];
    a2[0]=x0_.x+y0_.x; a2[1]=x0_.y+y0_.y; a2[2]=x0_.z+y0_.z; a2[3]=x0_.w+y0_.w;
    a2[4]=x1_.x+y1_.x; a2[5]=x1_.y+y1_.y; a2[6]=x1_.z+y1_.z; a2[7]=x1_.w+y1_.w;
  } else {
    #pragma unroll
    for (int o2=0;o2<8;++o2) a2[o2]=0.f;
  }
  int cb = half*32;
  for (int cc=0;cc<32;++cc){
    int c = cb+cc;
    float tn = sm[9028+c]*sm[c*133 + (c>>3) + p] + sm[9092+c];
    #pragma unroll
    for (int o2=0;o2<8;++o2) a2[o2] += sm[8516+o2*64+c]*tn;
  }
  __syncthreads();   // T1c reads done -> overlay exchange at [0,1152)
  if (half==1){
    #pragma unroll
    for (int o2=0;o2<8;++o2) sm[p*9+o2] = a2[o2];
  }
  __syncthreads();
  if (half==0){
    #pragma unroll
    for (int o2=0;o2<8;++o2) a2[o2] += sm[p*9+o2];
    float nrm=0.f;
    #pragma unroll
    for (int o2=0;o2<8;++o2) nrm += a2[o2]*a2[o2];
    float inv = 1.0f/sqrtf(nrm);
    size_t pos = (size_t)b*PPP + lglob*KKK + k;
    if (interleaved){
      long long idx = (long long)pos*8;
      if (idx+8 <= out_cap){
        *(float4*)&out[idx]   = make_float4(a2[0]*inv, a2[4]*inv, a2[1]*inv, a2[5]*inv);
        *(float4*)&out[idx+4] = make_float4(a2[2]*inv, a2[6]*inv, a2[3]*inv, a2[7]*inv);
      }
    } else {
      long long idx = (long long)pos*4;
      if (idx+4 <= out_cap)
        *(float4*)&out[idx] = make_float4(a2[0]*inv, a2[1]*inv, a2[2]*inv, a2[3]*inv);
    }
  }
}

// K6-SMALL: recompute T1 via t1_tile (round-4 proven fallback).
__global__ __launch_bounds__(256) void k_final(const float* __restrict__ ws,
                                               const float* __restrict__ P11,
                                               const float* __restrict__ P40,
                                               const float* __restrict__ P12,
                                               float* __restrict__ out,
                                               long long out_cap, int interleaved){
  __shared__ float sm[9156];
  int bid=blockIdx.x, b=bid>>3, pblk=bid&7, tid=threadIdx.x;
  int og=tid&7, pg=tid>>3, lloc=pg>>2, c0=og*8;
  for (int t=tid;t<512;t+=256) sm[8516+t] = 2.0f*P12[t];
  if (tid<64) sm[9028+tid]=ws[OFF_S1+tid];
  else if (tid<128) sm[9092+(tid-64)]=ws[OFF_T1+(tid-64)];
  float acc[8][4];
  t1_tile(sm, ws, P11, P40, b, pblk, tid, acc, og, pg, lloc, c0);
  __syncthreads();
  {
    int kg = pg&3;
    #pragma unroll
    for (int i=0;i<4;++i){
      int p = lloc*16 + kg*4 + i;
      #pragma unroll
      for (int j=0;j<8;++j) sm[(c0+j)*133 + og + p] = acc[j][i];
    }
  }
  __syncthreads();
  final_epilogue(ws, sm, b, pblk, tid, out, out_cap, interleaved);
}

extern "C" void kernel_launch(void* const* d_in, const int* in_sizes, int n_in,
                              void* d_out, int out_size, void* d_ws, size_t ws_size,
                              hipStream_t stream) {
  if (n_in < 15) return;
  if (in_sizes[0] != BRR*4096 || in_sizes[1] != BRR*4096) return;
  if (in_sizes[4] != 512)  return;   // P4_0 (64,8)
  if (in_sizes[7] != 4096) return;   // P1_1 (64,64)
  if (in_sizes[12] != 512) return;   // P1_2 (8,64)
  if (ws_size < (size_t)WS_FLOATS*4) return;   // clean fail, not a fault

  const float* Hr   = (const float*)d_in[0];
  const float* Hi   = (const float*)d_in[1];
  const float* P4_0 = (const float*)d_in[4];
  const float* g0   = (const float*)d_in[5];
  const float* b0   = (const float*)d_in[6];
  const float* P1_1 = (const float*)d_in[7];
  const float* P2_1 = (const float*)d_in[8];
  const float* P4_1 = (const float*)d_in[9];
  const float* g1   = (const float*)d_in[10];
  const float* b1   = (const float*)d_in[11];
  const float* P1_2 = (const float*)d_in[12];
  const float* P2_2 = (const float*)d_in[13];
  const float* P4_2 = (const float*)d_in[14];
  float* ws  = (float*)d_ws;
  float* out = (float*)d_out;
  int interleaved = (out_size >= 4194304) ? 1 : 0;
  int big = (ws_size >= (size_t)WS_BIG*4) ? 1 : 0;   // T1-spill path needs ~155 MiB

  k_zero<<<4, 256, 0, stream>>>((float4*)(ws + OFF_SUM0), 4096/4);
  k_prep<<<BRR, 256, 0, stream>>>(Hr, Hi, P4_0, ws);
  if (big){
    k_xy1<<<2560, 256, 0, stream>>>(ws, P2_1, P4_1, g0, b0);
    k_pass1f<<<BRR*2, 256, 0, stream>>>(ws, P1_1, g0, b0);
    k_xy2s<<<BRR, 256, 0, stream>>>(ws, P2_2, P4_2, g1, b1, 1);
    k_final_big<<<BRR*8, 256, 0, stream>>>(ws, P1_2, g1, b1, out,
                                           (long long)out_size, interleaved);
  } else {
    k_bn<<<1, 64, 0, stream>>>(ws, g0, b0, OFF_SUM0, OFF_S0);
    k_xy1<<<2560, 256, 0, stream>>>(ws, P2_1, P4_1, g0, b0);
    k_pass1<<<BRR, 256, 0, stream>>>(ws, P1_1, P4_0);
    k_bn<<<1, 64, 0, stream>>>(ws, g1, b1, OFF_SUM1, OFF_S1);
    k_xy2s<<<BRR, 256, 0, stream>>>(ws, P2_2, P4_2, g1, b1, 0);
    k_final<<<BRR*8, 256, 0, stream>>>(ws, P1_1, P4_0, P1_2, out,
                                       (long long)out_size, interleaved);
  }
}

// Round 14
// 258.582 us; speedup vs baseline: 1.1785x; 1.0595x over previous
//
#include <hip/hip_runtime.h>
#include <math.h>

#define BRR 512
#define LLL 64
#define KKK 16
#define EEE 64
#define CC2 8
#define PPP 1024
#define BN_EPS 1e-5f
#define NSTRIPE 16

__device__ __forceinline__ float relu_f(float v){ return v>0.f?v:0.f; }
// Row-padded W1 layout: stride 68 + 4-float stagger per 8-row octet.
__device__ __forceinline__ int lds_row(int r){ return r*68 + (((r>>3)&7)<<2); }

// ---- d_ws float layout ----
#define OFF_HBL  0u          // [(b*64+l)*8+c2]            262144
#define OFF_HBK  262144u     // [(b*16+k)*8+c2]             65536
#define OFF_Y0   327680u     // [b*1024 + k*64+c]          524288
#define OFF_X1   851968u     // [(b*64+l)*64+c] M0L->X1   2097152
#define OFF_Y1   2949120u    // [b*1024 + k*64+o] M0K->Y1  524288
#define OFF_X2   3473408u    // [(b*64+l)*8+o2]            262144
#define OFF_Y2   3735552u    // [(b*16+k)*8+o2]             65536
#define OFF_M1L  3801088u    // pre-pass1: x0 (X08); post: raw k-mean of T1
#define OFF_M1K  5898240u    // [b*1024 + k*64+c] raw l-mean half0   524288
#define OFF_SUM0 6422528u
#define OFF_SSQ0 6423552u
#define OFF_SUM1 6424576u
#define OFF_SSQ1 6425600u
#define OFF_S0   6426624u
#define OFF_T0   6426688u
#define OFF_S1   6426752u
#define OFF_T1   6426816u
#define WS_FLOATS 6426880u   // 25,707,520 bytes (small/fallback footprint)
// ---- big-ws extension (only touched when ws_size >= WS_BIG*4) ----
#define OFF_M1KB 6426880u    // M1K half1 partial                    524288
#define OFF_T1S  6951168u    // raw T1 tiles [(b*8+pblk)*8192 + j*1024 + lane*4 + i]
#define WS_BIG   40505600u   // 162,022,400 bytes (~154.5 MiB)

// Inline BN0/BN1 finalize (redundant per block; same math as k_bn).
__device__ __forceinline__ void bn_inline(const float* __restrict__ ws,
                                          unsigned sumOff,
                                          const float* __restrict__ g_,
                                          const float* __restrict__ b_,
                                          int tid, float* sc_out, float* st_out){
  if (tid < 64){
    float s=0.f, ss=0.f;
    for (int i=0;i<NSTRIPE;++i){ s+=ws[sumOff+i*64+tid]; ss+=ws[sumOff+1024+i*64+tid]; }
    const float invN = 1.0f/((float)BRR*LLL*KKK);
    float mu=s*invN, var=ss*invN-mu*mu;
    float sc = g_[tid]/sqrtf(var+BN_EPS);
    sc_out[tid]=sc;
    st_out[tid]=b_[tid]-mu*sc;
  }
}

// ---------------------------------------------------------------------------
// K0: zero stat accumulators only (4096 floats).
__global__ void k_zero(float4* __restrict__ p, int n4){
  int t = blockIdx.x*256 + threadIdx.x;
  if (t < n4) p[t] = make_float4(0.f,0.f,0.f,0.f);
}

// K1: per-b prep. Loop-interchanged reductions: the 4/16 elements each
// thread owns all share c = tid&63, so the shared-c LDS operand is hoisted
// (M0K: 256->64 reads/thread; M0L: 256->16). Per-element accumulation order
// (over l / over k) is unchanged.
__global__ __launch_bounds__(256) void k_prep(const float* __restrict__ Hr,
                                              const float* __restrict__ Hi,
                                              const float* __restrict__ P40,
                                              float* __restrict__ ws){
  __shared__ float sm[9344];
  int b = blockIdx.x, tid = threadIdx.x;
  const float* hrg = Hr + (size_t)b*4096;
  const float* hig = Hi + (size_t)b*4096;
  for (int t4=tid;t4<1024;t4+=256){
    *(float4*)&sm[t4*4]      = *(const float4*)&hrg[t4*4];
    *(float4*)&sm[4096+t4*4] = *(const float4*)&hig[t4*4];
  }
  for (int t=tid;t<512;t+=256){ int c=t&63,j=t>>6; sm[8192+j*64+c]=P40[c*8+j]; }
  __syncthreads();
  for (int t=tid;t<512;t+=256){ int l=t>>3,c2=t&7;          // HbL [8704,9216)
    const float* src=sm+((c2<4)?0:4096); int u=c2&3;
    float s=0.f;
    #pragma unroll
    for(int k=0;k<16;++k) s+=src[(l*16+k)*4+u];
    sm[8704+t]=s*(1.f/16.f); }
  for (int t=tid;t<128;t+=256){ int k=t>>3,c2=t&7;          // HbK [9216,9344)
    const float* src=sm+((c2<4)?0:4096); int u=c2&3;
    float s=0.f;
    for(int l=0;l<64;++l) s+=src[(l*16+k)*4+u];
    sm[9216+t]=s*(1.f/64.f); }
  __syncthreads();
  for (int t=tid;t<1024;t+=256){ int k=t>>6,c=t&63; float s=0.f;   // y0 [4096,5120)
    #pragma unroll
    for(int j=0;j<8;++j) s+=sm[8192+j*64+c]*sm[9216+k*8+j];
    sm[4096+t]=0.1f*s; }
  for (int t=tid;t<4096;t+=256){ int l=t>>6,c=t&63; float s=0.f;   // x0 [0,4096)
    #pragma unroll
    for(int j=0;j<8;++j) s+=sm[8192+j*64+c]*sm[8704+l*8+j];
    sm[t]=0.1f*s; }
  __syncthreads();
  {                                     // M0K [5120,6144): c shared, l hoisted
    int c = tid&63;
    float yv[4], s[4];
    #pragma unroll
    for (int e=0;e<4;++e){ yv[e]=sm[4096+tid+e*256]; s[e]=0.f; }
    for (int l=0;l<64;++l){
      float xv = sm[l*64+c];
      #pragma unroll
      for (int e=0;e<4;++e) s[e]+=relu_f(xv+yv[e]);
    }
    #pragma unroll
    for (int e=0;e<4;++e) sm[5120+tid+e*256]=s[e]*(1.f/64.f);
  }
  float ssum=0.f, ssq=0.f;
  {                                     // M0L: c shared, k hoisted
    int c = tid&63;
    float xv[16], s[16];
    #pragma unroll
    for (int e=0;e<16;++e){ xv[e]=sm[tid+e*256]; s[e]=0.f; }
    for (int k=0;k<16;++k){
      float yv = sm[4096+k*64+c];
      #pragma unroll
      for (int e=0;e<16;++e){ float v=relu_f(xv[e]+yv); s[e]+=v; ssq+=v*v; }
    }
    #pragma unroll
    for (int e=0;e<16;++e){
      ssum+=s[e];
      ws[OFF_X1+(size_t)b*4096+tid+e*256]=s[e]*(1.f/16.f);   // M0L
    }
  }
  __syncthreads();
  sm[6144+tid]=ssum; sm[6400+tid]=ssq;
  __syncthreads();
  if (tid<64){
    float ts =sm[6144+tid]+sm[6208+tid]+sm[6272+tid]+sm[6336+tid];
    float tss=sm[6400+tid]+sm[6464+tid]+sm[6528+tid]+sm[6592+tid];
    int stripe = b & (NSTRIPE-1);
    atomicAdd(&ws[OFF_SUM0+stripe*64+tid], ts);
    atomicAdd(&ws[OFF_SSQ0+stripe*64+tid], tss);
  }
  for (int t4=tid;t4<128;t4+=256)
    *(float4*)&ws[OFF_HBL+(size_t)b*512+t4*4] = *(const float4*)&sm[8704+t4*4];
  for (int t=tid;t<128;t+=256)  ws[OFF_HBK+(size_t)b*128+t]=sm[9216+t];
  for (int t4=tid;t4<256;t4+=256)
    *(float4*)&ws[OFF_Y0+(size_t)b*1024+t4*4] = *(const float4*)&sm[4096+t4*4];
  for (int t4=tid;t4<256;t4+=256)
    *(float4*)&ws[OFF_Y1+(size_t)b*1024+t4*4] = *(const float4*)&sm[5120+t4*4];   // M0K
  for (int t4=tid;t4<1024;t4+=256)
    *(float4*)&ws[OFF_M1L+(size_t)b*4096+t4*4] = *(const float4*)&sm[t4*4];       // x0
}

// K2: finalize BN -> s,t (small path only; big path inlines).
__global__ void k_bn(float* __restrict__ ws, const float* __restrict__ g_,
                     const float* __restrict__ b_, unsigned sumOff, unsigned outOff){
  int tid = threadIdx.x;
  bn_inline(ws, sumOff, g_, b_, tid, ws+outOff, ws+outOff+64);
}

// K3: X1/Y1 in place over M0L/M0K. BN0 inlined; c-outer loop with 4 row
// accumulators: wt[c*65+o] read once per c (was 4x), 320 LDS reads/thread
// instead of 512. Per-row c-accumulation order unchanged.
__global__ __launch_bounds__(256) void k_xy1(float* __restrict__ ws,
                                             const float* __restrict__ P21,
                                             const float* __restrict__ P41,
                                             const float* __restrict__ g0,
                                             const float* __restrict__ b0){
  __shared__ float wt[4160], p41[512], mrow[1024], hbs[128], s0l[64], t0l[64];
  int bx = blockIdx.x, tid = threadIdx.x;
  for (int t4=tid;t4<1024;t4+=256){           // wt[c*65+o] = 2*P21[o*64+c]
    int o=t4>>4, c4=(t4&15)*4;
    float4 v = *(const float4*)&P21[o*64+c4];
    wt[(c4+0)*65+o]=2.f*v.x; wt[(c4+1)*65+o]=2.f*v.y;
    wt[(c4+2)*65+o]=2.f*v.z; wt[(c4+3)*65+o]=2.f*v.w;
  }
  for (int t=tid;t<512;t+=256)  p41[t] = P41[t];                        // [o*8+j]
  bn_inline(ws, OFF_SUM0, g0, b0, tid, s0l, t0l);
  bool isX = bx < 2048;
  int row0 = isX ? bx*16 : (bx-2048)*16;
  if (isX){
    for (int t4=tid;t4<256;t4+=256)
      *(float4*)&mrow[t4*4] = *(const float4*)&ws[OFF_X1+(size_t)row0*64+t4*4];
    if (tid<128) hbs[tid] = ws[OFF_HBL+(size_t)row0*8+tid];
  } else {
    for (int t4=tid;t4<256;t4+=256)
      *(float4*)&mrow[t4*4] = *(const float4*)&ws[OFF_Y1+(size_t)row0*64+t4*4];
    if (tid<128) hbs[tid] = ws[OFF_HBK+(size_t)row0*8+tid];
  }
  __syncthreads();
  for (int t=tid;t<1024;t+=256){ int c=t&63; mrow[t]=s0l[c]*mrow[t]+t0l[c]; }
  __syncthreads();
  int r4 = tid>>6, o = tid&63;
  float s[4]={0.f,0.f,0.f,0.f};
  for (int c=0;c<64;++c){
    float w = wt[c*65+o];
    #pragma unroll
    for (int rr=0;rr<4;++rr) s[rr] += w*mrow[(rr*4+r4)*64+c];
  }
  #pragma unroll
  for (int rr=0;rr<4;++rr){
    int rl = rr*4 + r4;
    float s2=0.f;
    #pragma unroll
    for (int j=0;j<8;++j) s2 += p41[o*8+j]*hbs[rl*8+j];
    float res = s[rr] + 0.1f*s2;
    if (isX) ws[OFF_X1+(size_t)(row0+rl)*64+o] = res;
    else     ws[OFF_Y1+(size_t)(row0+rl)*64+o] = res;
  }
}

// ---- T1 tile LDS map (small-path t1_tile) ----
#define T_W1   0
#define T_X08  4384
#define T_Y0   4896
#define T_X1   5984
#define T_Y1   6496
#define T_S0   7520
#define T_T0   7584
#define T_P4T0 7648
#define T_HB8  8160
#define T_END  8224

// c4 loop unroll-4: full x16 unroll -> VGPR 256 tier (r3); unroll 4 -> 76 (r4).
__device__ void t1_tile(float* sm, const float* __restrict__ ws,
                        const float* __restrict__ P11, const float* __restrict__ P40,
                        int b, int pblk, int tid,
                        float acc[8][4], int og, int pg, int lloc, int c0){
  for (int t=tid;t<4096;t+=256){ int o=t>>6,c=t&63; sm[T_W1+lds_row(o)+c]=2.0f*P11[t]; }
  for (int t=tid;t<1024;t+=256){ int k=t>>6,c=t&63; sm[T_Y0+k*68+c]=ws[OFF_Y0+(size_t)b*1024+t]; }
  for (int t=tid;t<512;t+=256)  sm[T_X1+t]=ws[OFF_X1+((size_t)b*64+pblk*8)*64+t];
  for (int t=tid;t<1024;t+=256) sm[T_Y1+t]=ws[OFF_Y1+(size_t)b*1024+t];
  for (int t=tid;t<512;t+=256){ int c=t&63,j=t>>6; sm[T_P4T0+j*64+c]=P40[c*8+j]; }
  if (tid<64){ sm[T_S0+tid]=ws[OFF_S0+tid]; sm[T_T0+tid]=ws[OFF_T0+tid]; }
  else if (tid<128){ int t2=tid-64; sm[T_HB8+t2]=ws[OFF_HBL+((size_t)b*64+pblk*8)*8+t2]; }
  __syncthreads();
  for (int e=tid;e<512;e+=256){ int l=e>>6,c=e&63; float s=0.f;
    #pragma unroll
    for(int j=0;j<8;++j) s += sm[T_P4T0+j*64+c]*sm[T_HB8+l*8+j];
    sm[T_X08+e]=0.1f*s; }
  __syncthreads();
  {
    float xb[8];
    *(float4*)&xb[0] = *(const float4*)&sm[T_X1 + lloc*64 + c0];
    *(float4*)&xb[4] = *(const float4*)&sm[T_X1 + lloc*64 + c0 + 4];
    #pragma unroll
    for (int i=0;i<4;++i){
      int k=(pg&3)*4+i;
      float yb[8];
      *(float4*)&yb[0] = *(const float4*)&sm[T_Y1 + k*64 + c0];
      *(float4*)&yb[4] = *(const float4*)&sm[T_Y1 + k*64 + c0 + 4];
      #pragma unroll
      for (int j=0;j<8;++j) acc[j][i]=xb[j]+yb[j];
    }
  }
  #pragma unroll 4
  for (int c4=0;c4<16;++c4){
    float4 xr  = *(const float4*)&sm[T_X08 + lloc*64 + c4*4];
    float4 s0v = *(const float4*)&sm[T_S0 + c4*4];
    float4 t0v = *(const float4*)&sm[T_T0 + c4*4];
    float4 aa[4];
    #pragma unroll
    for (int i=0;i<4;++i){
      int k=(pg&3)*4+i;
      float4 yr = *(const float4*)&sm[T_Y0 + k*68 + c4*4];
      aa[i].x = s0v.x*relu_f(xr.x+yr.x)+t0v.x;
      aa[i].y = s0v.y*relu_f(xr.y+yr.y)+t0v.y;
      aa[i].z = s0v.z*relu_f(xr.z+yr.z)+t0v.z;
      aa[i].w = s0v.w*relu_f(xr.w+yr.w)+t0v.w;
    }
    #pragma unroll
    for (int j=0;j<8;++j){
      float4 w = *(const float4*)&sm[T_W1 + lds_row(c0+j) + c4*4];
      #pragma unroll
      for (int i=0;i<4;++i)
        acc[j][i] += w.x*aa[i].x + w.y*aa[i].y + w.z*aa[i].z + w.w*aa[i].w;
    }
  }
  #pragma unroll
  for (int j=0;j<8;++j)
    #pragma unroll
    for (int i=0;i<4;++i) acc[j][i] = relu_f(acc[j][i]);
}

// ---- pass1f LDS map (big path, pair-slot X1/X08) ----
#define PD_W1   0      // [0,4384)  padded W (lds_row)
#define PD_Y0   4384   // [4384,5472)  16 x 68
#define PD_Y1   5472   // [5472,6496)
#define PD_X1D  6496   // [6496,7520)  2 slots x 512 (pblk pair)
#define PD_X08D 7520   // [7520,8544)  2 slots x 512
#define PD_CT   8544   // [8544,8608)
#define PD_S0   8608   // [8608,8672)
#define PD_T0   8672   // [8672,8736)
#define PD_TOT  8736   // 34.9 KB -> 4 blocks/CU

// K4-BIG v6 (r10/r11 proven, ~95-100us, VGPR 124): 2-pblk-per-thread
// blocking; BN0 inlined; ROW-MAJOR T1S store (tid*4 + j*1024 — folds to one
// base + constant immediates; the r12 c-major variant added address regs ->
// VGPR 132 crossed the 128 tier -> 40us regression. Do NOT touch.)
__global__ __launch_bounds__(256) void k_pass1f(float* __restrict__ ws,
                                                const float* __restrict__ P11,
                                                const float* __restrict__ g0,
                                                const float* __restrict__ b0){
  __shared__ float sm[PD_TOT];
  int b = blockIdx.x >> 1, h = blockIdx.x & 1;
  int pb0 = h*4;
  int tid=threadIdx.x;
  int og=tid&7, kg=(tid>>3)&3, lloc=tid>>5, c0=og*8, wv=tid>>6;
  // stage W (2*P11, float4), Y0 (stride 68), Y1; BN0 finalize inline
  for (int t4=tid;t4<1024;t4+=256){ int o=t4>>4,c=(t4&15)*4;
    float4 v = *(const float4*)&P11[o*64+c];
    v.x*=2.f; v.y*=2.f; v.z*=2.f; v.w*=2.f;
    *(float4*)&sm[PD_W1+lds_row(o)+c]=v; }
  for (int t4=tid;t4<256;t4+=256){
    float4 v = *(const float4*)&ws[OFF_Y0+(size_t)b*1024+t4*4];
    *(float4*)&sm[PD_Y0+(t4>>4)*68+((t4&15)*4)]=v; }
  for (int t4=tid;t4<256;t4+=256)
    *(float4*)&sm[PD_Y1+t4*4] = *(const float4*)&ws[OFF_Y1+(size_t)b*1024+t4*4];
  bn_inline(ws, OFF_SUM0, g0, b0, tid, sm+PD_S0, sm+PD_T0);
  // prologue: slots <- pair0 (pb0, pb0+1).
  {
    int po = tid>>7, idx = tid&127;
    float4 v1 = *(const float4*)&ws[OFF_X1 +((size_t)b*64+(pb0+po)*8)*64 + (size_t)idx*4];
    float4 v8 = *(const float4*)&ws[OFF_M1L+((size_t)b*64+(pb0+po)*8)*64 + (size_t)idx*4];
    *(float4*)&sm[PD_X1D  + po*512 + idx*4] = v1;
    *(float4*)&sm[PD_X08D + po*512 + idx*4] = v8;
  }
  __syncthreads();
  if (tid<64){                       // ct[o] from UNSCALED W
    float ct=0.f;
    for (int c=0;c<64;++c) ct += sm[PD_W1+lds_row(tid)+c]*sm[PD_T0+c];
    sm[PD_CT+tid]=ct;
  }
  __syncthreads();
  for (int t4=tid;t4<1024;t4+=256){ int o=t4>>4,c=(t4&15)*4;
    float4 w = *(float4*)&sm[PD_W1+lds_row(o)+c];
    float4 s = *(const float4*)&sm[PD_S0+c];
    w.x*=s.x; w.y*=s.y; w.z*=s.z; w.w*=s.w;
    *(float4*)&sm[PD_W1+lds_row(o)+c]=w; }
  float qsum[8], mk[8][4];
  #pragma unroll
  for (int j=0;j<8;++j){ qsum[j]=0.f;
    #pragma unroll
    for (int i=0;i<4;++i) mk[j][i]=0.f; }
  #pragma unroll 1
  for (int pr=0;pr<2;++pr){
    int pblkA = pb0 + 2*pr, pblkB = pblkA + 1;
    __syncthreads();   // slots ready (prologue / prev mid-pair write); W-scale done
    float4 n1, n8;     // prefetch next pair into regs (T14 split)
    if (pr==0){
      int po = tid>>7, idx = tid&127, pn = pb0 + 2 + po;
      n1 = *(const float4*)&ws[OFF_X1 +((size_t)b*64+pn*8)*64 + (size_t)idx*4];
      n8 = *(const float4*)&ws[OFF_M1L+((size_t)b*64+pn*8)*64 + (size_t)idx*4];
    }
    float accA[8][4], accB[8][4];
    {
      float xbA[8], xbB[8], ctv[8];
      *(float4*)&xbA[0] = *(const float4*)&sm[PD_X1D       + lloc*64 + c0];
      *(float4*)&xbA[4] = *(const float4*)&sm[PD_X1D       + lloc*64 + c0 + 4];
      *(float4*)&xbB[0] = *(const float4*)&sm[PD_X1D + 512 + lloc*64 + c0];
      *(float4*)&xbB[4] = *(const float4*)&sm[PD_X1D + 512 + lloc*64 + c0 + 4];
      *(float4*)&ctv[0] = *(const float4*)&sm[PD_CT + c0];
      *(float4*)&ctv[4] = *(const float4*)&sm[PD_CT + c0 + 4];
      #pragma unroll
      for (int i=0;i<4;++i){
        int k=kg*4+i;
        float yb[8];
        *(float4*)&yb[0] = *(const float4*)&sm[PD_Y1 + k*64 + c0];
        *(float4*)&yb[4] = *(const float4*)&sm[PD_Y1 + k*64 + c0 + 4];
        #pragma unroll
        for (int j=0;j<8;++j){
          float base = yb[j]+ctv[j];
          accA[j][i]=xbA[j]+base;
          accB[j][i]=xbB[j]+base;
        }
      }
    }
    #pragma unroll 2
    for (int c4=0;c4<16;++c4){
      float4 xrA = *(const float4*)&sm[PD_X08D       + lloc*64 + c4*4];
      float4 xrB = *(const float4*)&sm[PD_X08D + 512 + lloc*64 + c4*4];
      float4 aaA[4], aaB[4];
      #pragma unroll
      for (int i=0;i<4;++i){
        int k=kg*4+i;
        float4 yr = *(const float4*)&sm[PD_Y0 + k*68 + c4*4];
        aaA[i].x = relu_f(xrA.x+yr.x); aaB[i].x = relu_f(xrB.x+yr.x);
        aaA[i].y = relu_f(xrA.y+yr.y); aaB[i].y = relu_f(xrB.y+yr.y);
        aaA[i].z = relu_f(xrA.z+yr.z); aaB[i].z = relu_f(xrB.z+yr.z);
        aaA[i].w = relu_f(xrA.w+yr.w); aaB[i].w = relu_f(xrB.w+yr.w);
      }
      #pragma unroll
      for (int j=0;j<8;++j){
        float4 w = *(const float4*)&sm[PD_W1 + lds_row(c0+j) + c4*4];
        #pragma unroll
        for (int i=0;i<4;++i){
          accA[j][i] += w.x*aaA[i].x + w.y*aaA[i].y + w.z*aaA[i].z + w.w*aaA[i].w;
          accB[j][i] += w.x*aaB[i].x + w.y*aaB[i].y + w.z*aaB[i].z + w.w*aaB[i].w;
        }
      }
    }
    #pragma unroll
    for (int j=0;j<8;++j)
      #pragma unroll
      for (int i=0;i<4;++i){
        accA[j][i] = relu_f(accA[j][i]);
        accB[j][i] = relu_f(accB[j][i]);
      }
    // ---- raw-T1 spill (coalesced float4; row-major [j][tid][i]) ----
    {
      size_t tbA = OFF_T1S + ((size_t)b*8 + pblkA)*8192 + (size_t)tid*4;
      size_t tbB = OFF_T1S + ((size_t)b*8 + pblkB)*8192 + (size_t)tid*4;
      #pragma unroll
      for (int j=0;j<8;++j){
        *(float4*)&ws[tbA + j*1024] =
          make_float4(accA[j][0],accA[j][1],accA[j][2],accA[j][3]);
        *(float4*)&ws[tbB + j*1024] =
          make_float4(accB[j][0],accB[j][1],accB[j][2],accB[j][3]);
      }
    }
    // ---- fold into running register reductions (both tiles) ----
    float sjA[8], sjB[8];
    #pragma unroll
    for (int j=0;j<8;++j){
      sjA[j]=accA[j][0]+accA[j][1]+accA[j][2]+accA[j][3];
      sjB[j]=accB[j][0]+accB[j][1]+accB[j][2]+accB[j][3];
      qsum[j]+=accA[j][0]*accA[j][0]+accA[j][1]*accA[j][1]+accA[j][2]*accA[j][2]+accA[j][3]*accA[j][3];
      qsum[j]+=accB[j][0]*accB[j][0]+accB[j][1]*accB[j][1]+accB[j][2]*accB[j][2]+accB[j][3]*accB[j][3];
      #pragma unroll
      for (int i=0;i<4;++i) mk[j][i]+=accA[j][i]+accB[j][i];
    }
    // M1L: k-reduce over kg (tid bits 3,4), kg==0 lanes write both rows
    #pragma unroll
    for (int j=0;j<8;++j){
      float rA=sjA[j];
      rA += __shfl_xor(rA, 8, 64);
      rA += __shfl_xor(rA, 16, 64);
      sjA[j]=rA;
      float rB=sjB[j];
      rB += __shfl_xor(rB, 8, 64);
      rB += __shfl_xor(rB, 16, 64);
      sjB[j]=rB;
    }
    if (kg==0){
      const float inv16 = 1.f/16.f;
      size_t baseA = OFF_M1L + ((size_t)b*64 + pblkA*8 + lloc)*64 + c0;
      size_t baseB = OFF_M1L + ((size_t)b*64 + pblkB*8 + lloc)*64 + c0;
      *(float4*)&ws[baseA]   = make_float4(sjA[0]*inv16, sjA[1]*inv16, sjA[2]*inv16, sjA[3]*inv16);
      *(float4*)&ws[baseA+4] = make_float4(sjA[4]*inv16, sjA[5]*inv16, sjA[6]*inv16, sjA[7]*inv16);
      *(float4*)&ws[baseB]   = make_float4(sjB[0]*inv16, sjB[1]*inv16, sjB[2]*inv16, sjB[3]*inv16);
      *(float4*)&ws[baseB+4] = make_float4(sjB[4]*inv16, sjB[5]*inv16, sjB[6]*inv16, sjB[7]*inv16);
    }
    // mid-pair: all slot reads done -> write prefetched next pair
    if (pr==0){
      __syncthreads();
      int po = tid>>7, idx = tid&127;
      *(float4*)&sm[PD_X1D  + po*512 + idx*4] = n1;
      *(float4*)&sm[PD_X08D + po*512 + idx*4] = n8;
    }
  }
  __syncthreads();   // all GEMM/slot reads done -> overlay dead regions
  // M1K exchange: lloc-pair shfl, owner lanes write per-wave copies at
  // [0,4352) (dead W1). Writer stride 33 -> all 32 banks.
  #pragma unroll
  for (int j=0;j<8;++j){
    #pragma unroll
    for (int i=0;i<4;++i){
      float v = mk[j][i] + __shfl_xor(mk[j][i], 32, 64);
      if ((tid & 32)==0)
        sm[wv*1088 + (og*4+kg)*33 + i*8 + j] = v;
    }
  }
  // qsum exchange at [4384,6496) (dead Y0/Y1)
  {
    int pg = tid>>3;
    #pragma unroll
    for (int j=0;j<8;++j) sm[4384+(c0+j)*33+pg] = qsum[j];
  }
  __syncthreads();
  unsigned mko = h ? OFF_M1KB : OFF_M1K;
  float tsacc=0.f;
  #pragma unroll
  for (int r=0;r<4;++r){
    int e = tid + r*256;
    int k=e>>6, c=e&63;
    int a = ((c>>3)*4+(k>>2))*33 + (k&3)*8 + (c&7);
    float v = sm[a]+sm[1088+a]+sm[2176+a]+sm[3264+a];
    tsacc += v;
    ws[mko+(size_t)b*1024+e] = v*(1.f/64.f);
  }
  sm[6496 + (tid&63)*5 + wv] = tsacc;   // [6496,6816) dead X1d[0]
  __syncthreads();
  if (tid<64){
    float ts  = sm[6496+tid*5+0]+sm[6496+tid*5+1]+sm[6496+tid*5+2]+sm[6496+tid*5+3];
    float tss = 0.f;
    for (int g=0; g<32; ++g) tss += sm[4384+tid*33+g];
    int stripe = b & (NSTRIPE-1);
    atomicAdd(&ws[OFF_SUM1+stripe*64+tid], ts);
    atomicAdd(&ws[OFF_SSQ1+stripe*64+tid], tss);
  }
}

// K4-SMALL: fallback (round-4 proven): one block per b, LDS stride-33 MK RMW.
#define MK_OFF 8224
__global__ __launch_bounds__(256) void k_pass1(float* __restrict__ ws,
                                               const float* __restrict__ P11,
                                               const float* __restrict__ P40){
  __shared__ float sm[12576];
  int b=blockIdx.x, tid=threadIdx.x;
  int og=tid&7, pg=tid>>3, lloc=pg>>2, kg=pg&3, c0=og*8, wv=tid>>6;
  for (int t=tid;t<4096;t+=256){ int o=t>>6,c=t&63; sm[T_W1+lds_row(o)+c]=2.0f*P11[t]; }
  for (int t=tid;t<1024;t+=256){ int k=t>>6,c=t&63; sm[T_Y0+k*68+c]=ws[OFF_Y0+(size_t)b*1024+t]; }
  for (int t=tid;t<1024;t+=256) sm[T_Y1+t]=ws[OFF_Y1+(size_t)b*1024+t];
  for (int t=tid;t<512;t+=256){ int c=t&63,j=t>>6; sm[T_P4T0+j*64+c]=P40[c*8+j]; }
  if (tid<64){ sm[T_S0+tid]=ws[OFF_S0+tid]; sm[T_T0+tid]=ws[OFF_T0+tid]; }
  for (int t=tid;t<4352;t+=256) sm[MK_OFF+t]=0.f;
  float qsum[8];
  #pragma unroll
  for (int j=0;j<8;++j) qsum[j]=0.f;
  #pragma unroll 1
  for (int pblk=0;pblk<8;++pblk){
    __syncthreads();
    for (int t=tid;t<512;t+=256) sm[T_X1+t]=ws[OFF_X1+((size_t)b*64+pblk*8)*64+t];
    if (tid<64) sm[T_HB8+tid]=ws[OFF_HBL+((size_t)b*64+pblk*8)*8+tid];
    __syncthreads();
    for (int e=tid;e<512;e+=256){ int l=e>>6,c=e&63; float s=0.f;
      #pragma unroll
      for(int j=0;j<8;++j) s += sm[T_P4T0+j*64+c]*sm[T_HB8+l*8+j];
      sm[T_X08+e]=0.1f*s; }
    __syncthreads();
    float acc[8][4];
    {
      float xb[8];
      *(float4*)&xb[0] = *(const float4*)&sm[T_X1 + lloc*64 + c0];
      *(float4*)&xb[4] = *(const float4*)&sm[T_X1 + lloc*64 + c0 + 4];
      #pragma unroll
      for (int i=0;i<4;++i){
        int k=kg*4+i;
        float yb[8];
        *(float4*)&yb[0] = *(const float4*)&sm[T_Y1 + k*64 + c0];
        *(float4*)&yb[4] = *(const float4*)&sm[T_Y1 + k*64 + c0 + 4];
        #pragma unroll
        for (int j=0;j<8;++j) acc[j][i]=xb[j]+yb[j];
      }
    }
    #pragma unroll 4
    for (int c4=0;c4<16;++c4){
      float4 xr  = *(const float4*)&sm[T_X08 + lloc*64 + c4*4];
      float4 s0v = *(const float4*)&sm[T_S0 + c4*4];
      float4 t0v = *(const float4*)&sm[T_T0 + c4*4];
      float4 aa[4];
      #pragma unroll
      for (int i=0;i<4;++i){
        int k=kg*4+i;
        float4 yr = *(const float4*)&sm[T_Y0 + k*68 + c4*4];
        aa[i].x = s0v.x*relu_f(xr.x+yr.x)+t0v.x;
        aa[i].y = s0v.y*relu_f(xr.y+yr.y)+t0v.y;
        aa[i].z = s0v.z*relu_f(xr.z+yr.z)+t0v.z;
        aa[i].w = s0v.w*relu_f(xr.w+yr.w)+t0v.w;
      }
      #pragma unroll
      for (int j=0;j<8;++j){
        float4 w = *(const float4*)&sm[T_W1 + lds_row(c0+j) + c4*4];
        #pragma unroll
        for (int i=0;i<4;++i)
          acc[j][i] += w.x*aa[i].x + w.y*aa[i].y + w.z*aa[i].z + w.w*aa[i].w;
      }
    }
    #pragma unroll
    for (int j=0;j<8;++j)
      #pragma unroll
      for (int i=0;i<4;++i) acc[j][i] = relu_f(acc[j][i]);
    float sj[8];
    #pragma unroll
    for (int j=0;j<8;++j){
      sj[j]=acc[j][0]+acc[j][1]+acc[j][2]+acc[j][3];
      qsum[j]+=acc[j][0]*acc[j][0]+acc[j][1]*acc[j][1]+acc[j][2]*acc[j][2]+acc[j][3]*acc[j][3];
    }
    #pragma unroll
    for (int j=0;j<8;++j){
      float r=sj[j];
      r += __shfl_xor(r, 8, 64);
      r += __shfl_xor(r, 16, 64);
      sj[j]=r;
    }
    if (kg==0){
      const float inv16 = 1.f/16.f;
      float4 v0 = make_float4(sj[0]*inv16, sj[1]*inv16, sj[2]*inv16, sj[3]*inv16);
      float4 v1 = make_float4(sj[4]*inv16, sj[5]*inv16, sj[6]*inv16, sj[7]*inv16);
      size_t base = OFF_M1L + ((size_t)b*64 + pblk*8 + lloc)*64 + c0;
      *(float4*)&ws[base]   = v0;
      *(float4*)&ws[base+4] = v1;
    }
    #pragma unroll
    for (int j=0;j<8;++j){
      #pragma unroll
      for (int i=0;i<4;++i){
        float v = acc[j][i] + __shfl_xor(acc[j][i], 32, 64);
        if ((tid & 32)==0)
          sm[MK_OFF + wv*1088 + (og*4+kg)*33 + i*8 + j] += v;
      }
    }
  }
  __syncthreads();
  float tsacc=0.f;
  #pragma unroll
  for (int r=0;r<4;++r){
    int e = tid + r*256;
    int k=e>>6, c=e&63;
    int a = ((c>>3)*4+(k>>2))*33 + (k&3)*8 + (c&7);
    float v = sm[MK_OFF+a]+sm[MK_OFF+1088+a]+sm[MK_OFF+2176+a]+sm[MK_OFF+3264+a];
    tsacc += v;
    ws[OFF_M1K+(size_t)b*1024+e] = v*(1.f/64.f);
  }
  __syncthreads();
  sm[8224 + (tid&63)*5 + wv] = tsacc;
  #pragma unroll
  for (int j=0;j<8;++j) sm[8544+(c0+j)*33+pg] = qsum[j];
  __syncthreads();
  if (tid<64){
    float ts  = sm[8224+tid*5+0]+sm[8224+tid*5+1]+sm[8224+tid*5+2]+sm[8224+tid*5+3];
    float tss = 0.f;
    for (int g=0; g<32; ++g) tss += sm[8544+tid*33+g];
    int stripe = b & (NSTRIPE-1);
    atomicAdd(&ws[OFF_SUM1+stripe*64+tid], ts);
    atomicAdd(&ws[OFF_SSQ1+stripe*64+tid], tss);
  }
}

// K5: tiny per-b pass: X2/Y2 from raw M1L/M1K + BN1 (inlined). No atomics.
__global__ __launch_bounds__(256) void k_xy2s(float* __restrict__ ws,
                                              const float* __restrict__ P22,
                                              const float* __restrict__ P42,
                                              const float* __restrict__ g1,
                                              const float* __restrict__ b1,
                                              int two){
  __shared__ float mln[4352];   // [l][68] : s1*M1L+t1
  __shared__ float mkn[1088];   // [k][68] : s1*M1K+t1
  __shared__ float w2[512];     // [c*8+o2] = 2*P22[o2][c]
  __shared__ float p42s[64];    // [o2*8+j]
  __shared__ float hbl[512];    // [l*8+j]
  __shared__ float hbk[128];    // [k*8+j]
  __shared__ float s1l[64], t1l[64];
  int b = blockIdx.x, tid = threadIdx.x;
  bn_inline(ws, OFF_SUM1, g1, b1, tid, s1l, t1l);
  for (int t=tid;t<512;t+=256) w2[t] = 2.0f*P22[(t&7)*64 + (t>>3)];
  if (tid>=64 && tid<128) p42s[tid-64] = P42[tid-64];
  for (int t=tid;t<512;t+=256) hbl[t] = ws[OFF_HBL+(size_t)b*512+t];
  if (tid>=128 && tid<256 && tid-128<128) hbk[tid-128] = ws[OFF_HBK+(size_t)b*128+(tid-128)];
  __syncthreads();
  for (int t=tid;t<4096;t+=256){ int l=t>>6,c=t&63;
    mln[l*68+c] = s1l[c]*ws[OFF_M1L+(size_t)b*4096+t] + t1l[c]; }
  for (int t=tid;t<1024;t+=256){ int k=t>>6,c=t&63;
    float mv = ws[OFF_M1K+(size_t)b*1024+t];
    if (two) mv += ws[OFF_M1KB+(size_t)b*1024+t];
    mkn[k*68+c] = s1l[c]*mv + t1l[c]; }
  __syncthreads();
  for (int t=tid;t<512;t+=256){
    int l=t>>3, o2=t&7;
    float s=0.f;
    for (int c=0;c<64;++c) s += w2[c*8+o2]*mln[l*68+c];
    float s2=0.f;
    #pragma unroll
    for (int j=0;j<8;++j) s2 += p42s[o2*8+j]*hbl[l*8+j];
    ws[OFF_X2+(size_t)b*512+t] = s + 0.1f*s2;
  }
  if (tid<128){
    int k=tid>>3, o2=tid&7;
    float s=0.f;
    for (int c=0;c<64;++c) s += w2[c*8+o2]*mkn[k*68+c];
    float s2=0.f;
    #pragma unroll
    for (int j=0;j<8;++j) s2 += p42s[o2*8+j]*hbk[k*8+j];
    ws[OFF_Y2+(size_t)b*128+tid] = s + 0.1f*s2;
  }
}

// ---- shared epilogue (small path, 128 active threads; 133-stride T1c) ----
__device__ __forceinline__ void final_epilogue(const float* __restrict__ ws,
                                               float* sm, int b, int pblk, int tid,
                                               float* __restrict__ out,
                                               long long out_cap, int interleaved){
  if (tid < 128){
    int p = tid, k = p & 15, lglob = pblk*8 + (p>>4);
    float a2[8];
    {
      const float* xp = ws + OFF_X2 + ((size_t)b*64+lglob)*8;
      const float* yp = ws + OFF_Y2 + ((size_t)b*16+k)*8;
      float4 x0_ = *(const float4*)&xp[0];
      float4 x1_ = *(const float4*)&xp[4];
      float4 y0_ = *(const float4*)&yp[0];
      float4 y1_ = *(const float4*)&yp[4];
      a2[0]=x0_.x+y0_.x; a2[1]=x0_.y+y0_.y; a2[2]=x0_.z+y0_.z; a2[3]=x0_.w+y0_.w;
      a2[4]=x1_.x+y1_.x; a2[5]=x1_.y+y1_.y; a2[6]=x1_.z+y1_.z; a2[7]=x1_.w+y1_.w;
    }
    for (int c=0;c<64;++c){
      float tn = sm[9028+c]*sm[c*133 + (c>>3) + p] + sm[9092+c];   // s1*T1+t1
      #pragma unroll
      for (int o2=0;o2<8;++o2) a2[o2] += sm[8516+o2*64+c]*tn;
    }
    float nrm=0.f;
    #pragma unroll
    for (int o2=0;o2<8;++o2) nrm += a2[o2]*a2[o2];
    float inv = 1.0f/sqrtf(nrm);
    size_t pos = (size_t)b*PPP + lglob*KKK + k;
    if (interleaved){
      long long idx = (long long)pos*8;
      if (idx+8 <= out_cap){
        *(float4*)&out[idx]   = make_float4(a2[0]*inv, a2[4]*inv, a2[1]*inv, a2[5]*inv);
        *(float4*)&out[idx+4] = make_float4(a2[2]*inv, a2[6]*inv, a2[3]*inv, a2[7]*inv);
      }
    } else {
      long long idx = (long long)pos*4;
      if (idx+4 <= out_cap)
        *(float4*)&out[idx] = make_float4(a2[0]*inv, a2[1]*inv, a2[2]*inv, a2[3]*inv);
    }
  }
}

// K6-BIG: stream stored raw T1 (row-major) -> T1c LDS; BN1 inlined; epilogue
// c-loop split across thread halves, combine via stride-9 LDS exchange.
__global__ __launch_bounds__(256) void k_final_big(const float* __restrict__ ws,
                                                   const float* __restrict__ P12,
                                                   const float* __restrict__ g1,
                                                   const float* __restrict__ b1,
                                                   float* __restrict__ out,
                                                   long long out_cap, int interleaved){
  __shared__ float sm[9156];
  int bid=blockIdx.x, b=bid>>3, pblk=bid&7, tid=threadIdx.x;
  for (int t=tid;t<512;t+=256) sm[8516+t] = 2.0f*P12[t];
  bn_inline(ws, OFF_SUM1, g1, b1, tid, sm+9028, sm+9092);
  {
    size_t base = OFF_T1S + ((size_t)b*8 + pblk)*8192;
    for (int t4=tid;t4<2048;t4+=256){
      float4 v = *(const float4*)&ws[base + (size_t)t4*4];
      int j = t4>>8, lane = t4&255;
      int c = (lane&7)*8 + j;
      int pb = (lane>>5)*16 + ((lane>>3)&3)*4;
      int o = c*133 + (c>>3) + pb;
      sm[o+0]=v.x; sm[o+1]=v.y; sm[o+2]=v.z; sm[o+3]=v.w;
    }
  }
  __syncthreads();
  int half = tid>>7, p = tid&127;
  int k = p & 15, lglob = pblk*8 + (p>>4);
  float a2[8];
  if (half==0){
    const float* xp = ws + OFF_X2 + ((size_t)b*64+lglob)*8;
    const float* yp = ws + OFF_Y2 + ((size_t)b*16+k)*8;
    float4 x0_ = *(const float4*)&xp[0];
    float4 x1_ = *(const float4*)&xp[4];
    float4 y0_ = *(const float4*)&yp[0];
    float4 y1_ = *(const float4*)&yp[4];
    a2[0]=x0_.x+y0_.x; a2[1]=x0_.y+y0_.y; a2[2]=x0_.z+y0_.z; a2[3]=x0_.w+y0_.w;
    a2[4]=x1_.x+y1_.x; a2[5]=x1_.y+y1_.y; a2[6]=x1_.z+y1_.z; a2[7]=x1_.w+y1_.w;
  } else {
    #pragma unroll
    for (int o2=0;o2<8;++o2) a2[o2]=0.f;
  }
  int cb = half*32;
  for (int cc=0;cc<32;++cc){
    int c = cb+cc;
    float tn = sm[9028+c]*sm[c*133 + (c>>3) + p] + sm[9092+c];
    #pragma unroll
    for (int o2=0;o2<8;++o2) a2[o2] += sm[8516+o2*64+c]*tn;
  }
  __syncthreads();   // T1c reads done -> overlay exchange at [0,1152)
  if (half==1){
    #pragma unroll
    for (int o2=0;o2<8;++o2) sm[p*9+o2] = a2[o2];
  }
  __syncthreads();
  if (half==0){
    #pragma unroll
    for (int o2=0;o2<8;++o2) a2[o2] += sm[p*9+o2];
    float nrm=0.f;
    #pragma unroll
    for (int o2=0;o2<8;++o2) nrm += a2[o2]*a2[o2];
    float inv = 1.0f/sqrtf(nrm);
    size_t pos = (size_t)b*PPP + lglob*KKK + k;
    if (interleaved){
      long long idx = (long long)pos*8;
      if (idx+8 <= out_cap){
        *(float4*)&out[idx]   = make_float4(a2[0]*inv, a2[4]*inv, a2[1]*inv, a2[5]*inv);
        *(float4*)&out[idx+4] = make_float4(a2[2]*inv, a2[6]*inv, a2[3]*inv, a2[7]*inv);
      }
    } else {
      long long idx = (long long)pos*4;
      if (idx+4 <= out_cap)
        *(float4*)&out[idx] = make_float4(a2[0]*inv, a2[1]*inv, a2[2]*inv, a2[3]*inv);
    }
  }
}

// K6-SMALL: recompute T1 via t1_tile (round-4 proven fallback).
__global__ __launch_bounds__(256) void k_final(const float* __restrict__ ws,
                                               const float* __restrict__ P11,
                                               const float* __restrict__ P40,
                                               const float* __restrict__ P12,
                                               float* __restrict__ out,
                                               long long out_cap, int interleaved){
  __shared__ float sm[9156];
  int bid=blockIdx.x, b=bid>>3, pblk=bid&7, tid=threadIdx.x;
  int og=tid&7, pg=tid>>3, lloc=pg>>2, c0=og*8;
  for (int t=tid;t<512;t+=256) sm[8516+t] = 2.0f*P12[t];
  if (tid<64) sm[9028+tid]=ws[OFF_S1+tid];
  else if (tid<128) sm[9092+(tid-64)]=ws[OFF_T1+(tid-64)];
  float acc[8][4];
  t1_tile(sm, ws, P11, P40, b, pblk, tid, acc, og, pg, lloc, c0);
  __syncthreads();
  {
    int kg = pg&3;
    #pragma unroll
    for (int i=0;i<4;++i){
      int p = lloc*16 + kg*4 + i;
      #pragma unroll
      for (int j=0;j<8;++j) sm[(c0+j)*133 + og + p] = acc[j][i];
    }
  }
  __syncthreads();
  final_epilogue(ws, sm, b, pblk, tid, out, out_cap, interleaved);
}

extern "C" void kernel_launch(void* const* d_in, const int* in_sizes, int n_in,
                              void* d_out, int out_size, void* d_ws, size_t ws_size,
                              hipStream_t stream) {
  if (n_in < 15) return;
  if (in_sizes[0] != BRR*4096 || in_sizes[1] != BRR*4096) return;
  if (in_sizes[4] != 512)  return;   // P4_0 (64,8)
  if (in_sizes[7] != 4096) return;   // P1_1 (64,64)
  if (in_sizes[12] != 512) return;   // P1_2 (8,64)
  if (ws_size < (size_t)WS_FLOATS*4) return;   // clean fail, not a fault

  const float* Hr   = (const float*)d_in[0];
  const float* Hi   = (const float*)d_in[1];
  const float* P4_0 = (const float*)d_in[4];
  const float* g0   = (const float*)d_in[5];
  const float* b0   = (const float*)d_in[6];
  const float* P1_1 = (const float*)d_in[7];
  const float* P2_1 = (const float*)d_in[8];
  const float* P4_1 = (const float*)d_in[9];
  const float* g1   = (const float*)d_in[10];
  const float* b1   = (const float*)d_in[11];
  const float* P1_2 = (const float*)d_in[12];
  const float* P2_2 = (const float*)d_in[13];
  const float* P4_2 = (const float*)d_in[14];
  float* ws  = (float*)d_ws;
  float* out = (float*)d_out;
  int interleaved = (out_size >= 4194304) ? 1 : 0;
  int big = (ws_size >= (size_t)WS_BIG*4) ? 1 : 0;   // T1-spill path needs ~155 MiB

  k_zero<<<4, 256, 0, stream>>>((float4*)(ws + OFF_SUM0), 4096/4);
  k_prep<<<BRR, 256, 0, stream>>>(Hr, Hi, P4_0, ws);
  if (big){
    k_xy1<<<2560, 256, 0, stream>>>(ws, P2_1, P4_1, g0, b0);
    k_pass1f<<<BRR*2, 256, 0, stream>>>(ws, P1_1, g0, b0);
    k_xy2s<<<BRR, 256, 0, stream>>>(ws, P2_2, P4_2, g1, b1, 1);
    k_final_big<<<BRR*8, 256, 0, stream>>>(ws, P1_2, g1, b1, out,
                                           (long long)out_size, interleaved);
  } else {
    k_bn<<<1, 64, 0, stream>>>(ws, g0, b0, OFF_SUM0, OFF_S0);
    k_xy1<<<2560, 256, 0, stream>>>(ws, P2_1, P4_1, g0, b0);
    k_pass1<<<BRR, 256, 0, stream>>>(ws, P1_1, P4_0);
    k_bn<<<1, 64, 0, stream>>>(ws, g1, b1, OFF_SUM1, OFF_S1);
    k_xy2s<<<BRR, 256, 0, stream>>>(ws, P2_2, P4_2, g1, b1, 0);
    k_final<<<BRR*8, 256, 0, stream>>>(ws, P1_1, P4_0, P1_2, out,
                                       (long long)out_size, interleaved);
  }
}

// Round 15
// 258.251 us; speedup vs baseline: 1.1800x; 1.0013x over previous
//
#include <hip/hip_runtime.h>
#include <math.h>

#define BRR 512
#define LLL 64
#define KKK 16
#define EEE 64
#define CC2 8
#define PPP 1024
#define BN_EPS 1e-5f
#define NSTRIPE 16

__device__ __forceinline__ float relu_f(float v){ return v>0.f?v:0.f; }
// Row-padded W1 layout: stride 68 + 4-float stagger per 8-row octet.
__device__ __forceinline__ int lds_row(int r){ return r*68 + (((r>>3)&7)<<2); }

// ---- d_ws float layout ----
#define OFF_HBL  0u          // [(b*64+l)*8+c2]            262144
#define OFF_HBK  262144u     // [(b*16+k)*8+c2]             65536
#define OFF_Y0   327680u     // [b*1024 + k*64+c]          524288
#define OFF_X1   851968u     // [(b*64+l)*64+c] M0L->X1   2097152
#define OFF_Y1   2949120u    // [b*1024 + k*64+o] M0K->Y1  524288
#define OFF_X2   3473408u    // [(b*64+l)*8+o2]            262144
#define OFF_Y2   3735552u    // [(b*16+k)*8+o2]             65536
#define OFF_M1L  3801088u    // pre-pass1: x0 (X08); post: raw k-mean of T1
#define OFF_M1K  5898240u    // [b*1024 + k*64+c] raw l-mean half0   524288
#define OFF_SUM0 6422528u
#define OFF_SSQ0 6423552u
#define OFF_SUM1 6424576u
#define OFF_SSQ1 6425600u
#define OFF_S0   6426624u
#define OFF_T0   6426688u
#define OFF_S1   6426752u
#define OFF_T1   6426816u
#define WS_FLOATS 6426880u   // 25,707,520 bytes (small/fallback footprint)
// ---- big-ws extension (only touched when ws_size >= WS_BIG*4) ----
#define OFF_M1KB 6426880u    // M1K half1 partial                    524288
#define OFF_T1S  6951168u    // raw T1 tiles [(b*8+pblk)*8192 + j*1024 + lane*4 + i]
#define WS_BIG   40505600u   // 162,022,400 bytes (~154.5 MiB)

// Inline BN0/BN1 finalize (redundant per block; same math as k_bn).
__device__ __forceinline__ void bn_inline(const float* __restrict__ ws,
                                          unsigned sumOff,
                                          const float* __restrict__ g_,
                                          const float* __restrict__ b_,
                                          int tid, float* sc_out, float* st_out){
  if (tid < 64){
    float s=0.f, ss=0.f;
    for (int i=0;i<NSTRIPE;++i){ s+=ws[sumOff+i*64+tid]; ss+=ws[sumOff+1024+i*64+tid]; }
    const float invN = 1.0f/((float)BRR*LLL*KKK);
    float mu=s*invN, var=ss*invN-mu*mu;
    float sc = g_[tid]/sqrtf(var+BN_EPS);
    sc_out[tid]=sc;
    st_out[tid]=b_[tid]-mu*sc;
  }
}

// ---------------------------------------------------------------------------
// K0: zero stat accumulators only (4096 floats).
__global__ void k_zero(float4* __restrict__ p, int n4){
  int t = blockIdx.x*256 + threadIdx.x;
  if (t < n4) p[t] = make_float4(0.f,0.f,0.f,0.f);
}

// K1: per-b prep. Loop-interchanged reductions (r14). HbL k-loop start
// rotated by l: bank = ((k+l)*4+u) mod 32 -> wave spreads over all 32 banks
// (was 16-way: (k*4+u) independent of l). Same 16 terms, rotated sum order.
__global__ __launch_bounds__(256) void k_prep(const float* __restrict__ Hr,
                                              const float* __restrict__ Hi,
                                              const float* __restrict__ P40,
                                              float* __restrict__ ws){
  __shared__ float sm[9344];
  int b = blockIdx.x, tid = threadIdx.x;
  const float* hrg = Hr + (size_t)b*4096;
  const float* hig = Hi + (size_t)b*4096;
  for (int t4=tid;t4<1024;t4+=256){
    *(float4*)&sm[t4*4]      = *(const float4*)&hrg[t4*4];
    *(float4*)&sm[4096+t4*4] = *(const float4*)&hig[t4*4];
  }
  for (int t=tid;t<512;t+=256){ int c=t&63,j=t>>6; sm[8192+j*64+c]=P40[c*8+j]; }
  __syncthreads();
  for (int t=tid;t<512;t+=256){ int l=t>>3,c2=t&7;          // HbL [8704,9216)
    const float* src=sm+((c2<4)?0:4096); int u=c2&3;
    float s=0.f;
    #pragma unroll
    for(int kk=0;kk<16;++kk){ int k=(kk+l)&15; s+=src[(l*16+k)*4+u]; }
    sm[8704+t]=s*(1.f/16.f); }
  for (int t=tid;t<128;t+=256){ int k=t>>3,c2=t&7;          // HbK [9216,9344)
    const float* src=sm+((c2<4)?0:4096); int u=c2&3;
    float s=0.f;
    for(int l=0;l<64;++l) s+=src[(l*16+k)*4+u];
    sm[9216+t]=s*(1.f/64.f); }
  __syncthreads();
  for (int t=tid;t<1024;t+=256){ int k=t>>6,c=t&63; float s=0.f;   // y0 [4096,5120)
    #pragma unroll
    for(int j=0;j<8;++j) s+=sm[8192+j*64+c]*sm[9216+k*8+j];
    sm[4096+t]=0.1f*s; }
  for (int t=tid;t<4096;t+=256){ int l=t>>6,c=t&63; float s=0.f;   // x0 [0,4096)
    #pragma unroll
    for(int j=0;j<8;++j) s+=sm[8192+j*64+c]*sm[8704+l*8+j];
    sm[t]=0.1f*s; }
  __syncthreads();
  {                                     // M0K [5120,6144): c shared, l hoisted
    int c = tid&63;
    float yv[4], s[4];
    #pragma unroll
    for (int e=0;e<4;++e){ yv[e]=sm[4096+tid+e*256]; s[e]=0.f; }
    for (int l=0;l<64;++l){
      float xv = sm[l*64+c];
      #pragma unroll
      for (int e=0;e<4;++e) s[e]+=relu_f(xv+yv[e]);
    }
    #pragma unroll
    for (int e=0;e<4;++e) sm[5120+tid+e*256]=s[e]*(1.f/64.f);
  }
  float ssum=0.f, ssq=0.f;
  {                                     // M0L: c shared, k hoisted
    int c = tid&63;
    float xv[16], s[16];
    #pragma unroll
    for (int e=0;e<16;++e){ xv[e]=sm[tid+e*256]; s[e]=0.f; }
    for (int k=0;k<16;++k){
      float yv = sm[4096+k*64+c];
      #pragma unroll
      for (int e=0;e<16;++e){ float v=relu_f(xv[e]+yv); s[e]+=v; ssq+=v*v; }
    }
    #pragma unroll
    for (int e=0;e<16;++e){
      ssum+=s[e];
      ws[OFF_X1+(size_t)b*4096+tid+e*256]=s[e]*(1.f/16.f);   // M0L
    }
  }
  __syncthreads();
  sm[6144+tid]=ssum; sm[6400+tid]=ssq;
  __syncthreads();
  if (tid<64){
    float ts =sm[6144+tid]+sm[6208+tid]+sm[6272+tid]+sm[6336+tid];
    float tss=sm[6400+tid]+sm[6464+tid]+sm[6528+tid]+sm[6592+tid];
    int stripe = b & (NSTRIPE-1);
    atomicAdd(&ws[OFF_SUM0+stripe*64+tid], ts);
    atomicAdd(&ws[OFF_SSQ0+stripe*64+tid], tss);
  }
  for (int t4=tid;t4<128;t4+=256)
    *(float4*)&ws[OFF_HBL+(size_t)b*512+t4*4] = *(const float4*)&sm[8704+t4*4];
  for (int t=tid;t<128;t+=256)  ws[OFF_HBK+(size_t)b*128+t]=sm[9216+t];
  for (int t4=tid;t4<256;t4+=256)
    *(float4*)&ws[OFF_Y0+(size_t)b*1024+t4*4] = *(const float4*)&sm[4096+t4*4];
  for (int t4=tid;t4<256;t4+=256)
    *(float4*)&ws[OFF_Y1+(size_t)b*1024+t4*4] = *(const float4*)&sm[5120+t4*4];   // M0K
  for (int t4=tid;t4<1024;t4+=256)
    *(float4*)&ws[OFF_M1L+(size_t)b*4096+t4*4] = *(const float4*)&sm[t4*4];       // x0
}

// K2: finalize BN -> s,t (small path only; big path inlines).
__global__ void k_bn(float* __restrict__ ws, const float* __restrict__ g_,
                     const float* __restrict__ b_, unsigned sumOff, unsigned outOff){
  int tid = threadIdx.x;
  bn_inline(ws, sumOff, g_, b_, tid, ws+outOff, ws+outOff+64);
}

// K3: X1/Y1 in place over M0L/M0K. BN0 inlined; c-outer loop with 4 row
// accumulators (r14); coalesced float4 P21 staging into stride-65 wt.
__global__ __launch_bounds__(256) void k_xy1(float* __restrict__ ws,
                                             const float* __restrict__ P21,
                                             const float* __restrict__ P41,
                                             const float* __restrict__ g0,
                                             const float* __restrict__ b0){
  __shared__ float wt[4160], p41[512], mrow[1024], hbs[128], s0l[64], t0l[64];
  int bx = blockIdx.x, tid = threadIdx.x;
  for (int t4=tid;t4<1024;t4+=256){           // wt[c*65+o] = 2*P21[o*64+c]
    int o=t4>>4, c4=(t4&15)*4;
    float4 v = *(const float4*)&P21[o*64+c4];
    wt[(c4+0)*65+o]=2.f*v.x; wt[(c4+1)*65+o]=2.f*v.y;
    wt[(c4+2)*65+o]=2.f*v.z; wt[(c4+3)*65+o]=2.f*v.w;
  }
  for (int t=tid;t<512;t+=256)  p41[t] = P41[t];                        // [o*8+j]
  bn_inline(ws, OFF_SUM0, g0, b0, tid, s0l, t0l);
  bool isX = bx < 2048;
  int row0 = isX ? bx*16 : (bx-2048)*16;
  if (isX){
    for (int t4=tid;t4<256;t4+=256)
      *(float4*)&mrow[t4*4] = *(const float4*)&ws[OFF_X1+(size_t)row0*64+t4*4];
    if (tid<128) hbs[tid] = ws[OFF_HBL+(size_t)row0*8+tid];
  } else {
    for (int t4=tid;t4<256;t4+=256)
      *(float4*)&mrow[t4*4] = *(const float4*)&ws[OFF_Y1+(size_t)row0*64+t4*4];
    if (tid<128) hbs[tid] = ws[OFF_HBK+(size_t)row0*8+tid];
  }
  __syncthreads();
  for (int t=tid;t<1024;t+=256){ int c=t&63; mrow[t]=s0l[c]*mrow[t]+t0l[c]; }
  __syncthreads();
  int r4 = tid>>6, o = tid&63;
  float s[4]={0.f,0.f,0.f,0.f};
  for (int c=0;c<64;++c){
    float w = wt[c*65+o];
    #pragma unroll
    for (int rr=0;rr<4;++rr) s[rr] += w*mrow[(rr*4+r4)*64+c];
  }
  #pragma unroll
  for (int rr=0;rr<4;++rr){
    int rl = rr*4 + r4;
    float s2=0.f;
    #pragma unroll
    for (int j=0;j<8;++j) s2 += p41[o*8+j]*hbs[rl*8+j];
    float res = s[rr] + 0.1f*s2;
    if (isX) ws[OFF_X1+(size_t)(row0+rl)*64+o] = res;
    else     ws[OFF_Y1+(size_t)(row0+rl)*64+o] = res;
  }
}

// ---- T1 tile LDS map (small-path t1_tile) ----
#define T_W1   0
#define T_X08  4384
#define T_Y0   4896
#define T_X1   5984
#define T_Y1   6496
#define T_S0   7520
#define T_T0   7584
#define T_P4T0 7648
#define T_HB8  8160
#define T_END  8224

// c4 loop unroll-4: full x16 unroll -> VGPR 256 tier (r3); unroll 4 -> 76 (r4).
__device__ void t1_tile(float* sm, const float* __restrict__ ws,
                        const float* __restrict__ P11, const float* __restrict__ P40,
                        int b, int pblk, int tid,
                        float acc[8][4], int og, int pg, int lloc, int c0){
  for (int t=tid;t<4096;t+=256){ int o=t>>6,c=t&63; sm[T_W1+lds_row(o)+c]=2.0f*P11[t]; }
  for (int t=tid;t<1024;t+=256){ int k=t>>6,c=t&63; sm[T_Y0+k*68+c]=ws[OFF_Y0+(size_t)b*1024+t]; }
  for (int t=tid;t<512;t+=256)  sm[T_X1+t]=ws[OFF_X1+((size_t)b*64+pblk*8)*64+t];
  for (int t=tid;t<1024;t+=256) sm[T_Y1+t]=ws[OFF_Y1+(size_t)b*1024+t];
  for (int t=tid;t<512;t+=256){ int c=t&63,j=t>>6; sm[T_P4T0+j*64+c]=P40[c*8+j]; }
  if (tid<64){ sm[T_S0+tid]=ws[OFF_S0+tid]; sm[T_T0+tid]=ws[OFF_T0+tid]; }
  else if (tid<128){ int t2=tid-64; sm[T_HB8+t2]=ws[OFF_HBL+((size_t)b*64+pblk*8)*8+t2]; }
  __syncthreads();
  for (int e=tid;e<512;e+=256){ int l=e>>6,c=e&63; float s=0.f;
    #pragma unroll
    for(int j=0;j<8;++j) s += sm[T_P4T0+j*64+c]*sm[T_HB8+l*8+j];
    sm[T_X08+e]=0.1f*s; }
  __syncthreads();
  {
    float xb[8];
    *(float4*)&xb[0] = *(const float4*)&sm[T_X1 + lloc*64 + c0];
    *(float4*)&xb[4] = *(const float4*)&sm[T_X1 + lloc*64 + c0 + 4];
    #pragma unroll
    for (int i=0;i<4;++i){
      int k=(pg&3)*4+i;
      float yb[8];
      *(float4*)&yb[0] = *(const float4*)&sm[T_Y1 + k*64 + c0];
      *(float4*)&yb[4] = *(const float4*)&sm[T_Y1 + k*64 + c0 + 4];
      #pragma unroll
      for (int j=0;j<8;++j) acc[j][i]=xb[j]+yb[j];
    }
  }
  #pragma unroll 4
  for (int c4=0;c4<16;++c4){
    float4 xr  = *(const float4*)&sm[T_X08 + lloc*64 + c4*4];
    float4 s0v = *(const float4*)&sm[T_S0 + c4*4];
    float4 t0v = *(const float4*)&sm[T_T0 + c4*4];
    float4 aa[4];
    #pragma unroll
    for (int i=0;i<4;++i){
      int k=(pg&3)*4+i;
      float4 yr = *(const float4*)&sm[T_Y0 + k*68 + c4*4];
      aa[i].x = s0v.x*relu_f(xr.x+yr.x)+t0v.x;
      aa[i].y = s0v.y*relu_f(xr.y+yr.y)+t0v.y;
      aa[i].z = s0v.z*relu_f(xr.z+yr.z)+t0v.z;
      aa[i].w = s0v.w*relu_f(xr.w+yr.w)+t0v.w;
    }
    #pragma unroll
    for (int j=0;j<8;++j){
      float4 w = *(const float4*)&sm[T_W1 + lds_row(c0+j) + c4*4];
      #pragma unroll
      for (int i=0;i<4;++i)
        acc[j][i] += w.x*aa[i].x + w.y*aa[i].y + w.z*aa[i].z + w.w*aa[i].w;
    }
  }
  #pragma unroll
  for (int j=0;j<8;++j)
    #pragma unroll
    for (int i=0;i<4;++i) acc[j][i] = relu_f(acc[j][i]);
}

// ---- pass1f LDS map (big path, pair-slot X1/X08) ----
#define PD_W1   0      // [0,4384)  padded W (lds_row)
#define PD_Y0   4384   // [4384,5472)  16 x 68
#define PD_Y1   5472   // [5472,6496)
#define PD_X1D  6496   // [6496,7520)  2 slots x 512 (pblk pair)
#define PD_X08D 7520   // [7520,8544)  2 slots x 512
#define PD_CT   8544   // [8544,8608)
#define PD_S0   8608   // [8608,8672)
#define PD_T0   8672   // [8672,8736)
#define PD_TOT  8736   // 34.9 KB -> 4 blocks/CU

// K4-BIG v6 (r10/r11 proven, ~95-100us, VGPR 124): 2-pblk-per-thread
// blocking; BN0 inlined; ROW-MAJOR T1S store (tid*4 + j*1024 — folds to one
// base + constant immediates; the r12 c-major variant added address regs ->
// VGPR 132 crossed the 128 tier -> 40us regression. Do NOT touch.)
__global__ __launch_bounds__(256) void k_pass1f(float* __restrict__ ws,
                                                const float* __restrict__ P11,
                                                const float* __restrict__ g0,
                                                const float* __restrict__ b0){
  __shared__ float sm[PD_TOT];
  int b = blockIdx.x >> 1, h = blockIdx.x & 1;
  int pb0 = h*4;
  int tid=threadIdx.x;
  int og=tid&7, kg=(tid>>3)&3, lloc=tid>>5, c0=og*8, wv=tid>>6;
  // stage W (2*P11, float4), Y0 (stride 68), Y1; BN0 finalize inline
  for (int t4=tid;t4<1024;t4+=256){ int o=t4>>4,c=(t4&15)*4;
    float4 v = *(const float4*)&P11[o*64+c];
    v.x*=2.f; v.y*=2.f; v.z*=2.f; v.w*=2.f;
    *(float4*)&sm[PD_W1+lds_row(o)+c]=v; }
  for (int t4=tid;t4<256;t4+=256){
    float4 v = *(const float4*)&ws[OFF_Y0+(size_t)b*1024+t4*4];
    *(float4*)&sm[PD_Y0+(t4>>4)*68+((t4&15)*4)]=v; }
  for (int t4=tid;t4<256;t4+=256)
    *(float4*)&sm[PD_Y1+t4*4] = *(const float4*)&ws[OFF_Y1+(size_t)b*1024+t4*4];
  bn_inline(ws, OFF_SUM0, g0, b0, tid, sm+PD_S0, sm+PD_T0);
  // prologue: slots <- pair0 (pb0, pb0+1).
  {
    int po = tid>>7, idx = tid&127;
    float4 v1 = *(const float4*)&ws[OFF_X1 +((size_t)b*64+(pb0+po)*8)*64 + (size_t)idx*4];
    float4 v8 = *(const float4*)&ws[OFF_M1L+((size_t)b*64+(pb0+po)*8)*64 + (size_t)idx*4];
    *(float4*)&sm[PD_X1D  + po*512 + idx*4] = v1;
    *(float4*)&sm[PD_X08D + po*512 + idx*4] = v8;
  }
  __syncthreads();
  if (tid<64){                       // ct[o] from UNSCALED W
    float ct=0.f;
    for (int c=0;c<64;++c) ct += sm[PD_W1+lds_row(tid)+c]*sm[PD_T0+c];
    sm[PD_CT+tid]=ct;
  }
  __syncthreads();
  for (int t4=tid;t4<1024;t4+=256){ int o=t4>>4,c=(t4&15)*4;
    float4 w = *(float4*)&sm[PD_W1+lds_row(o)+c];
    float4 s = *(const float4*)&sm[PD_S0+c];
    w.x*=s.x; w.y*=s.y; w.z*=s.z; w.w*=s.w;
    *(float4*)&sm[PD_W1+lds_row(o)+c]=w; }
  float qsum[8], mk[8][4];
  #pragma unroll
  for (int j=0;j<8;++j){ qsum[j]=0.f;
    #pragma unroll
    for (int i=0;i<4;++i) mk[j][i]=0.f; }
  #pragma unroll 1
  for (int pr=0;pr<2;++pr){
    int pblkA = pb0 + 2*pr, pblkB = pblkA + 1;
    __syncthreads();   // slots ready (prologue / prev mid-pair write); W-scale done
    float4 n1, n8;     // prefetch next pair into regs (T14 split)
    if (pr==0){
      int po = tid>>7, idx = tid&127, pn = pb0 + 2 + po;
      n1 = *(const float4*)&ws[OFF_X1 +((size_t)b*64+pn*8)*64 + (size_t)idx*4];
      n8 = *(const float4*)&ws[OFF_M1L+((size_t)b*64+pn*8)*64 + (size_t)idx*4];
    }
    float accA[8][4], accB[8][4];
    {
      float xbA[8], xbB[8], ctv[8];
      *(float4*)&xbA[0] = *(const float4*)&sm[PD_X1D       + lloc*64 + c0];
      *(float4*)&xbA[4] = *(const float4*)&sm[PD_X1D       + lloc*64 + c0 + 4];
      *(float4*)&xbB[0] = *(const float4*)&sm[PD_X1D + 512 + lloc*64 + c0];
      *(float4*)&xbB[4] = *(const float4*)&sm[PD_X1D + 512 + lloc*64 + c0 + 4];
      *(float4*)&ctv[0] = *(const float4*)&sm[PD_CT + c0];
      *(float4*)&ctv[4] = *(const float4*)&sm[PD_CT + c0 + 4];
      #pragma unroll
      for (int i=0;i<4;++i){
        int k=kg*4+i;
        float yb[8];
        *(float4*)&yb[0] = *(const float4*)&sm[PD_Y1 + k*64 + c0];
        *(float4*)&yb[4] = *(const float4*)&sm[PD_Y1 + k*64 + c0 + 4];
        #pragma unroll
        for (int j=0;j<8;++j){
          float base = yb[j]+ctv[j];
          accA[j][i]=xbA[j]+base;
          accB[j][i]=xbB[j]+base;
        }
      }
    }
    #pragma unroll 2
    for (int c4=0;c4<16;++c4){
      float4 xrA = *(const float4*)&sm[PD_X08D       + lloc*64 + c4*4];
      float4 xrB = *(const float4*)&sm[PD_X08D + 512 + lloc*64 + c4*4];
      float4 aaA[4], aaB[4];
      #pragma unroll
      for (int i=0;i<4;++i){
        int k=kg*4+i;
        float4 yr = *(const float4*)&sm[PD_Y0 + k*68 + c4*4];
        aaA[i].x = relu_f(xrA.x+yr.x); aaB[i].x = relu_f(xrB.x+yr.x);
        aaA[i].y = relu_f(xrA.y+yr.y); aaB[i].y = relu_f(xrB.y+yr.y);
        aaA[i].z = relu_f(xrA.z+yr.z); aaB[i].z = relu_f(xrB.z+yr.z);
        aaA[i].w = relu_f(xrA.w+yr.w); aaB[i].w = relu_f(xrB.w+yr.w);
      }
      #pragma unroll
      for (int j=0;j<8;++j){
        float4 w = *(const float4*)&sm[PD_W1 + lds_row(c0+j) + c4*4];
        #pragma unroll
        for (int i=0;i<4;++i){
          accA[j][i] += w.x*aaA[i].x + w.y*aaA[i].y + w.z*aaA[i].z + w.w*aaA[i].w;
          accB[j][i] += w.x*aaB[i].x + w.y*aaB[i].y + w.z*aaB[i].z + w.w*aaB[i].w;
        }
      }
    }
    #pragma unroll
    for (int j=0;j<8;++j)
      #pragma unroll
      for (int i=0;i<4;++i){
        accA[j][i] = relu_f(accA[j][i]);
        accB[j][i] = relu_f(accB[j][i]);
      }
    // ---- raw-T1 spill (coalesced float4; row-major [j][tid][i]) ----
    {
      size_t tbA = OFF_T1S + ((size_t)b*8 + pblkA)*8192 + (size_t)tid*4;
      size_t tbB = OFF_T1S + ((size_t)b*8 + pblkB)*8192 + (size_t)tid*4;
      #pragma unroll
      for (int j=0;j<8;++j){
        *(float4*)&ws[tbA + j*1024] =
          make_float4(accA[j][0],accA[j][1],accA[j][2],accA[j][3]);
        *(float4*)&ws[tbB + j*1024] =
          make_float4(accB[j][0],accB[j][1],accB[j][2],accB[j][3]);
      }
    }
    // ---- fold into running register reductions (both tiles) ----
    float sjA[8], sjB[8];
    #pragma unroll
    for (int j=0;j<8;++j){
      sjA[j]=accA[j][0]+accA[j][1]+accA[j][2]+accA[j][3];
      sjB[j]=accB[j][0]+accB[j][1]+accB[j][2]+accB[j][3];
      qsum[j]+=accA[j][0]*accA[j][0]+accA[j][1]*accA[j][1]+accA[j][2]*accA[j][2]+accA[j][3]*accA[j][3];
      qsum[j]+=accB[j][0]*accB[j][0]+accB[j][1]*accB[j][1]+accB[j][2]*accB[j][2]+accB[j][3]*accB[j][3];
      #pragma unroll
      for (int i=0;i<4;++i) mk[j][i]+=accA[j][i]+accB[j][i];
    }
    // M1L: k-reduce over kg (tid bits 3,4), kg==0 lanes write both rows
    #pragma unroll
    for (int j=0;j<8;++j){
      float rA=sjA[j];
      rA += __shfl_xor(rA, 8, 64);
      rA += __shfl_xor(rA, 16, 64);
      sjA[j]=rA;
      float rB=sjB[j];
      rB += __shfl_xor(rB, 8, 64);
      rB += __shfl_xor(rB, 16, 64);
      sjB[j]=rB;
    }
    if (kg==0){
      const float inv16 = 1.f/16.f;
      size_t baseA = OFF_M1L + ((size_t)b*64 + pblkA*8 + lloc)*64 + c0;
      size_t baseB = OFF_M1L + ((size_t)b*64 + pblkB*8 + lloc)*64 + c0;
      *(float4*)&ws[baseA]   = make_float4(sjA[0]*inv16, sjA[1]*inv16, sjA[2]*inv16, sjA[3]*inv16);
      *(float4*)&ws[baseA+4] = make_float4(sjA[4]*inv16, sjA[5]*inv16, sjA[6]*inv16, sjA[7]*inv16);
      *(float4*)&ws[baseB]   = make_float4(sjB[0]*inv16, sjB[1]*inv16, sjB[2]*inv16, sjB[3]*inv16);
      *(float4*)&ws[baseB+4] = make_float4(sjB[4]*inv16, sjB[5]*inv16, sjB[6]*inv16, sjB[7]*inv16);
    }
    // mid-pair: all slot reads done -> write prefetched next pair
    if (pr==0){
      __syncthreads();
      int po = tid>>7, idx = tid&127;
      *(float4*)&sm[PD_X1D  + po*512 + idx*4] = n1;
      *(float4*)&sm[PD_X08D + po*512 + idx*4] = n8;
    }
  }
  __syncthreads();   // all GEMM/slot reads done -> overlay dead regions
  // M1K exchange: lloc-pair shfl, owner lanes write per-wave copies at
  // [0,4352) (dead W1). Writer stride 33 -> all 32 banks.
  #pragma unroll
  for (int j=0;j<8;++j){
    #pragma unroll
    for (int i=0;i<4;++i){
      float v = mk[j][i] + __shfl_xor(mk[j][i], 32, 64);
      if ((tid & 32)==0)
        sm[wv*1088 + (og*4+kg)*33 + i*8 + j] = v;
    }
  }
  // qsum exchange at [4384,6496) (dead Y0/Y1)
  {
    int pg = tid>>3;
    #pragma unroll
    for (int j=0;j<8;++j) sm[4384+(c0+j)*33+pg] = qsum[j];
  }
  __syncthreads();
  unsigned mko = h ? OFF_M1KB : OFF_M1K;
  float tsacc=0.f;
  #pragma unroll
  for (int r=0;r<4;++r){
    int e = tid + r*256;
    int k=e>>6, c=e&63;
    int a = ((c>>3)*4+(k>>2))*33 + (k&3)*8 + (c&7);
    float v = sm[a]+sm[1088+a]+sm[2176+a]+sm[3264+a];
    tsacc += v;
    ws[mko+(size_t)b*1024+e] = v*(1.f/64.f);
  }
  sm[6496 + (tid&63)*5 + wv] = tsacc;   // [6496,6816) dead X1d[0]
  __syncthreads();
  if (tid<64){
    float ts  = sm[6496+tid*5+0]+sm[6496+tid*5+1]+sm[6496+tid*5+2]+sm[6496+tid*5+3];
    float tss = 0.f;
    for (int g=0; g<32; ++g) tss += sm[4384+tid*33+g];
    int stripe = b & (NSTRIPE-1);
    atomicAdd(&ws[OFF_SUM1+stripe*64+tid], ts);
    atomicAdd(&ws[OFF_SSQ1+stripe*64+tid], tss);
  }
}

// K4-SMALL: fallback (round-4 proven): one block per b, LDS stride-33 MK RMW.
#define MK_OFF 8224
__global__ __launch_bounds__(256) void k_pass1(float* __restrict__ ws,
                                               const float* __restrict__ P11,
                                               const float* __restrict__ P40){
  __shared__ float sm[12576];
  int b=blockIdx.x, tid=threadIdx.x;
  int og=tid&7, pg=tid>>3, lloc=pg>>2, kg=pg&3, c0=og*8, wv=tid>>6;
  for (int t=tid;t<4096;t+=256){ int o=t>>6,c=t&63; sm[T_W1+lds_row(o)+c]=2.0f*P11[t]; }
  for (int t=tid;t<1024;t+=256){ int k=t>>6,c=t&63; sm[T_Y0+k*68+c]=ws[OFF_Y0+(size_t)b*1024+t]; }
  for (int t=tid;t<1024;t+=256) sm[T_Y1+t]=ws[OFF_Y1+(size_t)b*1024+t];
  for (int t=tid;t<512;t+=256){ int c=t&63,j=t>>6; sm[T_P4T0+j*64+c]=P40[c*8+j]; }
  if (tid<64){ sm[T_S0+tid]=ws[OFF_S0+tid]; sm[T_T0+tid]=ws[OFF_T0+tid]; }
  for (int t=tid;t<4352;t+=256) sm[MK_OFF+t]=0.f;
  float qsum[8];
  #pragma unroll
  for (int j=0;j<8;++j) qsum[j]=0.f;
  #pragma unroll 1
  for (int pblk=0;pblk<8;++pblk){
    __syncthreads();
    for (int t=tid;t<512;t+=256) sm[T_X1+t]=ws[OFF_X1+((size_t)b*64+pblk*8)*64+t];
    if (tid<64) sm[T_HB8+tid]=ws[OFF_HBL+((size_t)b*64+pblk*8)*8+tid];
    __syncthreads();
    for (int e=tid;e<512;e+=256){ int l=e>>6,c=e&63; float s=0.f;
      #pragma unroll
      for(int j=0;j<8;++j) s += sm[T_P4T0+j*64+c]*sm[T_HB8+l*8+j];
      sm[T_X08+e]=0.1f*s; }
    __syncthreads();
    float acc[8][4];
    {
      float xb[8];
      *(float4*)&xb[0] = *(const float4*)&sm[T_X1 + lloc*64 + c0];
      *(float4*)&xb[4] = *(const float4*)&sm[T_X1 + lloc*64 + c0 + 4];
      #pragma unroll
      for (int i=0;i<4;++i){
        int k=kg*4+i;
        float yb[8];
        *(float4*)&yb[0] = *(const float4*)&sm[T_Y1 + k*64 + c0];
        *(float4*)&yb[4] = *(const float4*)&sm[T_Y1 + k*64 + c0 + 4];
        #pragma unroll
        for (int j=0;j<8;++j) acc[j][i]=xb[j]+yb[j];
      }
    }
    #pragma unroll 4
    for (int c4=0;c4<16;++c4){
      float4 xr  = *(const float4*)&sm[T_X08 + lloc*64 + c4*4];
      float4 s0v = *(const float4*)&sm[T_S0 + c4*4];
      float4 t0v = *(const float4*)&sm[T_T0 + c4*4];
      float4 aa[4];
      #pragma unroll
      for (int i=0;i<4;++i){
        int k=kg*4+i;
        float4 yr = *(const float4*)&sm[T_Y0 + k*68 + c4*4];
        aa[i].x = s0v.x*relu_f(xr.x+yr.x)+t0v.x;
        aa[i].y = s0v.y*relu_f(xr.y+yr.y)+t0v.y;
        aa[i].z = s0v.z*relu_f(xr.z+yr.z)+t0v.z;
        aa[i].w = s0v.w*relu_f(xr.w+yr.w)+t0v.w;
      }
      #pragma unroll
      for (int j=0;j<8;++j){
        float4 w = *(const float4*)&sm[T_W1 + lds_row(c0+j) + c4*4];
        #pragma unroll
        for (int i=0;i<4;++i)
          acc[j][i] += w.x*aa[i].x + w.y*aa[i].y + w.z*aa[i].z + w.w*aa[i].w;
      }
    }
    #pragma unroll
    for (int j=0;j<8;++j)
      #pragma unroll
      for (int i=0;i<4;++i) acc[j][i] = relu_f(acc[j][i]);
    float sj[8];
    #pragma unroll
    for (int j=0;j<8;++j){
      sj[j]=acc[j][0]+acc[j][1]+acc[j][2]+acc[j][3];
      qsum[j]+=acc[j][0]*acc[j][0]+acc[j][1]*acc[j][1]+acc[j][2]*acc[j][2]+acc[j][3]*acc[j][3];
    }
    #pragma unroll
    for (int j=0;j<8;++j){
      float r=sj[j];
      r += __shfl_xor(r, 8, 64);
      r += __shfl_xor(r, 16, 64);
      sj[j]=r;
    }
    if (kg==0){
      const float inv16 = 1.f/16.f;
      float4 v0 = make_float4(sj[0]*inv16, sj[1]*inv16, sj[2]*inv16, sj[3]*inv16);
      float4 v1 = make_float4(sj[4]*inv16, sj[5]*inv16, sj[6]*inv16, sj[7]*inv16);
      size_t base = OFF_M1L + ((size_t)b*64 + pblk*8 + lloc)*64 + c0;
      *(float4*)&ws[base]   = v0;
      *(float4*)&ws[base+4] = v1;
    }
    #pragma unroll
    for (int j=0;j<8;++j){
      #pragma unroll
      for (int i=0;i<4;++i){
        float v = acc[j][i] + __shfl_xor(acc[j][i], 32, 64);
        if ((tid & 32)==0)
          sm[MK_OFF + wv*1088 + (og*4+kg)*33 + i*8 + j] += v;
      }
    }
  }
  __syncthreads();
  float tsacc=0.f;
  #pragma unroll
  for (int r=0;r<4;++r){
    int e = tid + r*256;
    int k=e>>6, c=e&63;
    int a = ((c>>3)*4+(k>>2))*33 + (k&3)*8 + (c&7);
    float v = sm[MK_OFF+a]+sm[MK_OFF+1088+a]+sm[MK_OFF+2176+a]+sm[MK_OFF+3264+a];
    tsacc += v;
    ws[OFF_M1K+(size_t)b*1024+e] = v*(1.f/64.f);
  }
  __syncthreads();
  sm[8224 + (tid&63)*5 + wv] = tsacc;
  #pragma unroll
  for (int j=0;j<8;++j) sm[8544+(c0+j)*33+pg] = qsum[j];
  __syncthreads();
  if (tid<64){
    float ts  = sm[8224+tid*5+0]+sm[8224+tid*5+1]+sm[8224+tid*5+2]+sm[8224+tid*5+3];
    float tss = 0.f;
    for (int g=0; g<32; ++g) tss += sm[8544+tid*33+g];
    int stripe = b & (NSTRIPE-1);
    atomicAdd(&ws[OFF_SUM1+stripe*64+tid], ts);
    atomicAdd(&ws[OFF_SSQ1+stripe*64+tid], tss);
  }
}

// K5: tiny per-b pass: X2/Y2 from raw M1L/M1K + BN1 (inlined). No atomics.
// Staging loops float4-vectorized (M1L/M1K/HbL/HbK; addresses 16B-aligned:
// 68 = 4*17, c0 multiple of 4).
__global__ __launch_bounds__(256) void k_xy2s(float* __restrict__ ws,
                                              const float* __restrict__ P22,
                                              const float* __restrict__ P42,
                                              const float* __restrict__ g1,
                                              const float* __restrict__ b1,
                                              int two){
  __shared__ float mln[4352];   // [l][68] : s1*M1L+t1
  __shared__ float mkn[1088];   // [k][68] : s1*M1K+t1
  __shared__ float w2[512];     // [c*8+o2] = 2*P22[o2][c]
  __shared__ float p42s[64];    // [o2*8+j]
  __shared__ float hbl[512];    // [l*8+j]
  __shared__ float hbk[128];    // [k*8+j]
  __shared__ float s1l[64], t1l[64];
  int b = blockIdx.x, tid = threadIdx.x;
  bn_inline(ws, OFF_SUM1, g1, b1, tid, s1l, t1l);
  for (int t=tid;t<512;t+=256) w2[t] = 2.0f*P22[(t&7)*64 + (t>>3)];
  if (tid>=64 && tid<128) p42s[tid-64] = P42[tid-64];
  for (int t4=tid;t4<128;t4+=256)
    *(float4*)&hbl[t4*4] = *(const float4*)&ws[OFF_HBL+(size_t)b*512+t4*4];
  if (tid>=128 && tid<160){
    int t4 = tid-128;
    *(float4*)&hbk[t4*4] = *(const float4*)&ws[OFF_HBK+(size_t)b*128+t4*4];
  }
  __syncthreads();
  for (int t4=tid;t4<1024;t4+=256){
    int l=t4>>4, c0=(t4&15)*4;
    float4 mv = *(const float4*)&ws[OFF_M1L+(size_t)b*4096+t4*4];
    float4 sc = *(const float4*)&s1l[c0];
    float4 tc = *(const float4*)&t1l[c0];
    float4 r = make_float4(sc.x*mv.x+tc.x, sc.y*mv.y+tc.y,
                           sc.z*mv.z+tc.z, sc.w*mv.w+tc.w);
    *(float4*)&mln[l*68+c0] = r;
  }
  for (int t4=tid;t4<256;t4+=256){
    int k=t4>>4, c0=(t4&15)*4;
    float4 mv = *(const float4*)&ws[OFF_M1K+(size_t)b*1024+t4*4];
    if (two){
      float4 mb = *(const float4*)&ws[OFF_M1KB+(size_t)b*1024+t4*4];
      mv.x+=mb.x; mv.y+=mb.y; mv.z+=mb.z; mv.w+=mb.w;
    }
    float4 sc = *(const float4*)&s1l[c0];
    float4 tc = *(const float4*)&t1l[c0];
    float4 r = make_float4(sc.x*mv.x+tc.x, sc.y*mv.y+tc.y,
                           sc.z*mv.z+tc.z, sc.w*mv.w+tc.w);
    *(float4*)&mkn[k*68+c0] = r;
  }
  __syncthreads();
  for (int t=tid;t<512;t+=256){
    int l=t>>3, o2=t&7;
    float s=0.f;
    for (int c=0;c<64;++c) s += w2[c*8+o2]*mln[l*68+c];
    float s2=0.f;
    #pragma unroll
    for (int j=0;j<8;++j) s2 += p42s[o2*8+j]*hbl[l*8+j];
    ws[OFF_X2+(size_t)b*512+t] = s + 0.1f*s2;
  }
  if (tid<128){
    int k=tid>>3, o2=tid&7;
    float s=0.f;
    for (int c=0;c<64;++c) s += w2[c*8+o2]*mkn[k*68+c];
    float s2=0.f;
    #pragma unroll
    for (int j=0;j<8;++j) s2 += p42s[o2*8+j]*hbk[k*8+j];
    ws[OFF_Y2+(size_t)b*128+tid] = s + 0.1f*s2;
  }
}

// ---- shared epilogue (small path, 128 active threads; 133-stride T1c) ----
__device__ __forceinline__ void final_epilogue(const float* __restrict__ ws,
                                               float* sm, int b, int pblk, int tid,
                                               float* __restrict__ out,
                                               long long out_cap, int interleaved){
  if (tid < 128){
    int p = tid, k = p & 15, lglob = pblk*8 + (p>>4);
    float a2[8];
    {
      const float* xp = ws + OFF_X2 + ((size_t)b*64+lglob)*8;
      const float* yp = ws + OFF_Y2 + ((size_t)b*16+k)*8;
      float4 x0_ = *(const float4*)&xp[0];
      float4 x1_ = *(const float4*)&xp[4];
      float4 y0_ = *(const float4*)&yp[0];
      float4 y1_ = *(const float4*)&yp[4];
      a2[0]=x0_.x+y0_.x; a2[1]=x0_.y+y0_.y; a2[2]=x0_.z+y0_.z; a2[3]=x0_.w+y0_.w;
      a2[4]=x1_.x+y1_.x; a2[5]=x1_.y+y1_.y; a2[6]=x1_.z+y1_.z; a2[7]=x1_.w+y1_.w;
    }
    for (int c=0;c<64;++c){
      float tn = sm[9028+c]*sm[c*133 + (c>>3) + p] + sm[9092+c];   // s1*T1+t1
      #pragma unroll
      for (int o2=0;o2<8;++o2) a2[o2] += sm[8516+o2*64+c]*tn;
    }
    float nrm=0.f;
    #pragma unroll
    for (int o2=0;o2<8;++o2) nrm += a2[o2]*a2[o2];
    float inv = 1.0f/sqrtf(nrm);
    size_t pos = (size_t)b*PPP + lglob*KKK + k;
    if (interleaved){
      long long idx = (long long)pos*8;
      if (idx+8 <= out_cap){
        *(float4*)&out[idx]   = make_float4(a2[0]*inv, a2[4]*inv, a2[1]*inv, a2[5]*inv);
        *(float4*)&out[idx+4] = make_float4(a2[2]*inv, a2[6]*inv, a2[3]*inv, a2[7]*inv);
      }
    } else {
      long long idx = (long long)pos*4;
      if (idx+4 <= out_cap)
        *(float4*)&out[idx] = make_float4(a2[0]*inv, a2[1]*inv, a2[2]*inv, a2[3]*inv);
    }
  }
}

// K6-BIG: stream stored raw T1 (row-major) -> T1c LDS; BN1 inlined; epilogue
// c-loop split across thread halves, combine via stride-9 LDS exchange.
__global__ __launch_bounds__(256) void k_final_big(const float* __restrict__ ws,
                                                   const float* __restrict__ P12,
                                                   const float* __restrict__ g1,
                                                   const float* __restrict__ b1,
                                                   float* __restrict__ out,
                                                   long long out_cap, int interleaved){
  __shared__ float sm[9156];
  int bid=blockIdx.x, b=bid>>3, pblk=bid&7, tid=threadIdx.x;
  for (int t=tid;t<512;t+=256) sm[8516+t] = 2.0f*P12[t];
  bn_inline(ws, OFF_SUM1, g1, b1, tid, sm+9028, sm+9092);
  {
    size_t base = OFF_T1S + ((size_t)b*8 + pblk)*8192;
    for (int t4=tid;t4<2048;t4+=256){
      float4 v = *(const float4*)&ws[base + (size_t)t4*4];
      int j = t4>>8, lane = t4&255;
      int c = (lane&7)*8 + j;
      int pb = (lane>>5)*16 + ((lane>>3)&3)*4;
      int o = c*133 + (c>>3) + pb;
      sm[o+0]=v.x; sm[o+1]=v.y; sm[o+2]=v.z; sm[o+3]=v.w;
    }
  }
  __syncthreads();
  int half = tid>>7, p = tid&127;
  int k = p & 15, lglob = pblk*8 + (p>>4);
  float a2[8];
  if (half==0){
    const float* xp = ws + OFF_X2 + ((size_t)b*64+lglob)*8;
    const float* yp = ws + OFF_Y2 + ((size_t)b*16+k)*8;
    float4 x0_ = *(const float4*)&xp[0];
    float4 x1_ = *(const float4*)&xp[4];
    float4 y0_ = *(const float4*)&yp[0];
    float4 y1_ = *(const float4*)&yp[4];
    a2[0]=x0_.x+y0_.x; a2[1]=x0_.y+y0_.y; a2[2]=x0_.z+y0_.z; a2[3]=x0_.w+y0_.w;
    a2[4]=x1_.x+y1_.x; a2[5]=x1_.y+y1_.y; a2[6]=x1_.z+y1_.z; a2[7]=x1_.w+y1_.w;
  } else {
    #pragma unroll
    for (int o2=0;o2<8;++o2) a2[o2]=0.f;
  }
  int cb = half*32;
  for (int cc=0;cc<32;++cc){
    int c = cb+cc;
    float tn = sm[9028+c]*sm[c*133 + (c>>3) + p] + sm[9092+c];
    #pragma unroll
    for (int o2=0;o2<8;++o2) a2[o2] += sm[8516+o2*64+c]*tn;
  }
  __syncthreads();   // T1c reads done -> overlay exchange at [0,1152)
  if (half==1){
    #pragma unroll
    for (int o2=0;o2<8;++o2) sm[p*9+o2] = a2[o2];
  }
  __syncthreads();
  if (half==0){
    #pragma unroll
    for (int o2=0;o2<8;++o2) a2[o2] += sm[p*9+o2];
    float nrm=0.f;
    #pragma unroll
    for (int o2=0;o2<8;++o2) nrm += a2[o2]*a2[o2];
    float inv = 1.0f/sqrtf(nrm);
    size_t pos = (size_t)b*PPP + lglob*KKK + k;
    if (interleaved){
      long long idx = (long long)pos*8;
      if (idx+8 <= out_cap){
        *(float4*)&out[idx]   = make_float4(a2[0]*inv, a2[4]*inv, a2[1]*inv, a2[5]*inv);
        *(float4*)&out[idx+4] = make_float4(a2[2]*inv, a2[6]*inv, a2[3]*inv, a2[7]*inv);
      }
    } else {
      long long idx = (long long)pos*4;
      if (idx+4 <= out_cap)
        *(float4*)&out[idx] = make_float4(a2[0]*inv, a2[1]*inv, a2[2]*inv, a2[3]*inv);
    }
  }
}

// K6-SMALL: recompute T1 via t1_tile (round-4 proven fallback).
__global__ __launch_bounds__(256) void k_final(const float* __restrict__ ws,
                                               const float* __restrict__ P11,
                                               const float* __restrict__ P40,
                                               const float* __restrict__ P12,
                                               float* __restrict__ out,
                                               long long out_cap, int interleaved){
  __shared__ float sm[9156];
  int bid=blockIdx.x, b=bid>>3, pblk=bid&7, tid=threadIdx.x;
  int og=tid&7, pg=tid>>3, lloc=pg>>2, c0=og*8;
  for (int t=tid;t<512;t+=256) sm[8516+t] = 2.0f*P12[t];
  if (tid<64) sm[9028+tid]=ws[OFF_S1+tid];
  else if (tid<128) sm[9092+(tid-64)]=ws[OFF_T1+(tid-64)];
  float acc[8][4];
  t1_tile(sm, ws, P11, P40, b, pblk, tid, acc, og, pg, lloc, c0);
  __syncthreads();
  {
    int kg = pg&3;
    #pragma unroll
    for (int i=0;i<4;++i){
      int p = lloc*16 + kg*4 + i;
      #pragma unroll
      for (int j=0;j<8;++j) sm[(c0+j)*133 + og + p] = acc[j][i];
    }
  }
  __syncthreads();
  final_epilogue(ws, sm, b, pblk, tid, out, out_cap, interleaved);
}

extern "C" void kernel_launch(void* const* d_in, const int* in_sizes, int n_in,
                              void* d_out, int out_size, void* d_ws, size_t ws_size,
                              hipStream_t stream) {
  if (n_in < 15) return;
  if (in_sizes[0] != BRR*4096 || in_sizes[1] != BRR*4096) return;
  if (in_sizes[4] != 512)  return;   // P4_0 (64,8)
  if (in_sizes[7] != 4096) return;   // P1_1 (64,64)
  if (in_sizes[12] != 512) return;   // P1_2 (8,64)
  if (ws_size < (size_t)WS_FLOATS*4) return;   // clean fail, not a fault

  const float* Hr   = (const float*)d_in[0];
  const float* Hi   = (const float*)d_in[1];
  const float* P4_0 = (const float*)d_in[4];
  const float* g0   = (const float*)d_in[5];
  const float* b0   = (const float*)d_in[6];
  const float* P1_1 = (const float*)d_in[7];
  const float* P2_1 = (const float*)d_in[8];
  const float* P4_1 = (const float*)d_in[9];
  const float* g1   = (const float*)d_in[10];
  const float* b1   = (const float*)d_in[11];
  const float* P1_2 = (const float*)d_in[12];
  const float* P2_2 = (const float*)d_in[13];
  const float* P4_2 = (const float*)d_in[14];
  float* ws  = (float*)d_ws;
  float* out = (float*)d_out;
  int interleaved = (out_size >= 4194304) ? 1 : 0;
  int big = (ws_size >= (size_t)WS_BIG*4) ? 1 : 0;   // T1-spill path needs ~155 MiB

  k_zero<<<4, 256, 0, stream>>>((float4*)(ws + OFF_SUM0), 4096/4);
  k_prep<<<BRR, 256, 0, stream>>>(Hr, Hi, P4_0, ws);
  if (big){
    k_xy1<<<2560, 256, 0, stream>>>(ws, P2_1, P4_1, g0, b0);
    k_pass1f<<<BRR*2, 256, 0, stream>>>(ws, P1_1, g0, b0);
    k_xy2s<<<BRR, 256, 0, stream>>>(ws, P2_2, P4_2, g1, b1, 1);
    k_final_big<<<BRR*8, 256, 0, stream>>>(ws, P1_2, g1, b1, out,
                                           (long long)out_size, interleaved);
  } else {
    k_bn<<<1, 64, 0, stream>>>(ws, g0, b0, OFF_SUM0, OFF_S0);
    k_xy1<<<2560, 256, 0, stream>>>(ws, P2_1, P4_1, g0, b0);
    k_pass1<<<BRR, 256, 0, stream>>>(ws, P1_1, P4_0);
    k_bn<<<1, 64, 0, stream>>>(ws, g1, b1, OFF_SUM1, OFF_S1);
    k_xy2s<<<BRR, 256, 0, stream>>>(ws, P2_2, P4_2, g1, b1, 0);
    k_final<<<BRR*8, 256, 0, stream>>>(ws, P1_1, P4_0, P1_2, out,
                                       (long long)out_size, interleaved);
  }
}